// Round 18
// baseline (144.935 us; speedup 1.0000x reference)
//
#include <hip/hip_runtime.h>

#define N_NODES 50000
#define N_EDGES 800000
#define NPAIRS  65536

#define NBUCK 391          // ceil(N_NODES/128): coarse bucket = row>>7
#define RTILE 2048
#define RBLOCKS 391        // ceil(N_EDGES/RTILE)

typedef unsigned short ushort_t;
typedef unsigned int uint_t;
typedef unsigned long long u64_t;
typedef ushort_t ushort8v __attribute__((ext_vector_type(8)));
typedef short bf16x8 __attribute__((ext_vector_type(8)));
typedef float f32x4 __attribute__((ext_vector_type(4)));

__device__ inline ushort_t f2bf(float f) {
    uint_t u = __float_as_uint(f);
    u = (u + 0x7FFF + ((u >> 16) & 1)) >> 16;   // RTN-even
    return (ushort_t)u;
}
__device__ inline float bf2f(ushort_t b) {
    return __uint_as_float(((uint_t)b) << 16);
}

// ---------------- CSR build: block-staged bucket sort ----------------

__global__ __launch_bounds__(256) void pack_hist_kernel(const int* __restrict__ rows,
                                                        const int* __restrict__ cols,
                                                        const float* __restrict__ vals,
                                                        u64_t* __restrict__ tmpA,
                                                        int* __restrict__ blockhist, int e) {
    __shared__ int lh[NBUCK];
    int blk = blockIdx.x, t = threadIdx.x;
    for (int i = t; i < NBUCK; i += 256) lh[i] = 0;
    __syncthreads();
    int base = blk * RTILE;
#pragma unroll
    for (int k = 0; k < RTILE / 256; k++) {
        int idx = base + k * 256 + t;
        if (idx < e) {
            int r = rows[idx];
            uint_t payload = (uint_t)cols[idx] | ((uint_t)f2bf(vals[idx]) << 16);
            tmpA[idx] = ((u64_t)r << 32) | payload;
            atomicAdd(&lh[r >> 7], 1);
        }
    }
    __syncthreads();
    for (int d = t; d < NBUCK; d += 256) blockhist[d * RBLOCKS + blk] = lh[d];
}

__global__ __launch_bounds__(256) void scan_block_kernel(const int* __restrict__ cnt,
                                                         int* __restrict__ excl,
                                                         int* __restrict__ blksum, int n) {
    __shared__ int s[256];
    int tid = threadIdx.x;
    int i = blockIdx.x * 256 + tid;
    int v = (i < n) ? cnt[i] : 0;
    s[tid] = v; __syncthreads();
    for (int off = 1; off < 256; off <<= 1) {
        int t = (tid >= off) ? s[tid - off] : 0;
        __syncthreads();
        s[tid] += t;
        __syncthreads();
    }
    if (i < n) excl[i] = s[tid] - v;
    if (tid == 255) blksum[blockIdx.x] = s[255];
}

// single-block multi-chunk exclusive scan (in place)
__global__ __launch_bounds__(256) void scan_mid_kernel(int* __restrict__ data, int n) {
    __shared__ int s[256];
    __shared__ int carry;
    int t = threadIdx.x;
    if (t == 0) carry = 0;
    __syncthreads();
    for (int base = 0; base < n; base += 256) {
        int i = base + t;
        int v = (i < n) ? data[i] : 0;
        s[t] = v; __syncthreads();
        for (int off = 1; off < 256; off <<= 1) {
            int x = (t >= off) ? s[t - off] : 0;
            __syncthreads();
            s[t] += x;
            __syncthreads();
        }
        int excl = s[t] - v + carry;
        if (i < n) data[i] = excl;
        __syncthreads();
        if (t == 255) carry += s[255];
        __syncthreads();
    }
}

__global__ __launch_bounds__(256) void scan_add2_kernel(int* __restrict__ data,
                                                        const int* __restrict__ blksum, int n) {
    int i = blockIdx.x * 256 + threadIdx.x;
    if (i < n) data[i] += blksum[blockIdx.x];
}

__global__ __launch_bounds__(256) void radix_scatter_kernel(const u64_t* __restrict__ tmpA,
                                                            const int* __restrict__ gofs,
                                                            u64_t* __restrict__ tmpB, int e) {
    __shared__ u64_t stage[RTILE];          // 16 KB
    __shared__ int lh[NBUCK];
    __shared__ int lstart[NBUCK];
    __shared__ int lcur[NBUCK];
    int blk = blockIdx.x, t = threadIdx.x;
    for (int i = t; i < NBUCK; i += 256) lh[i] = 0;
    __syncthreads();
    int base = blk * RTILE;
    int cnt = min(RTILE, e - base);
    for (int k = t; k < cnt; k += 256) {
        int d = (int)(tmpA[base + k] >> 39);   // (row>>7)
        atomicAdd(&lh[d], 1);
    }
    __syncthreads();
    if (t == 0) {
        int s = 0;
        for (int d = 0; d < NBUCK; d++) { lstart[d] = s; s += lh[d]; }
    }
    __syncthreads();
    for (int i = t; i < NBUCK; i += 256) lcur[i] = lstart[i];
    __syncthreads();
    for (int k = t; k < cnt; k += 256) {
        u64_t it = tmpA[base + k];
        int d = (int)(it >> 39);
        int slot = atomicAdd(&lcur[d], 1);
        stage[slot] = it;
    }
    __syncthreads();
    for (int k = t; k < cnt; k += 256) {
        u64_t it = stage[k];
        int d = (int)(it >> 39);
        tmpB[gofs[d * RBLOCKS + blk] + (k - lstart[d])] = it;
    }
}

__global__ __launch_bounds__(256) void bucket_sort_kernel(const u64_t* __restrict__ tmpB,
                                                          const int* __restrict__ gofs,
                                                          uint_t* __restrict__ csr_edge,
                                                          int* __restrict__ row_ptr, int e, int n) {
    __shared__ uint_t stage[4096];
    __shared__ int lh[128];
    __shared__ int lstart[128];
    __shared__ int lcur[128];
    int d = blockIdx.x, t = threadIdx.x;
    int bstart = gofs[d * RBLOCKS];
    int bend = (d == NBUCK - 1) ? e : gofs[(d + 1) * RBLOCKS];
    int len = bend - bstart;
    for (int i = t; i < 128; i += 256) lh[i] = 0;
    __syncthreads();
    for (int k = t; k < len; k += 256) {
        int lr = (int)((tmpB[bstart + k] >> 32) & 127);
        atomicAdd(&lh[lr], 1);
    }
    __syncthreads();
    if (t == 0) {
        int s = 0;
        for (int j = 0; j < 128; j++) { lstart[j] = s; s += lh[j]; }
    }
    __syncthreads();
    if (t < 128) {
        int grow = d * 128 + t;
        if (grow <= n) row_ptr[grow] = bstart + lstart[t];
    }
    for (int i = t; i < 128; i += 256) lcur[i] = lstart[i];
    __syncthreads();
    for (int k = t; k < len; k += 256) {
        u64_t it = tmpB[bstart + k];
        int lr = (int)((it >> 32) & 127);
        int slot = atomicAdd(&lcur[lr], 1);
        stage[slot] = (uint_t)it;
    }
    __syncthreads();
    for (int k = t; k < len; k += 256) csr_edge[bstart + k] = stage[k];
}

// ---------------- W prep: Wt1 [c][k] bf16, Wt2 [c][k] bf16, Wtp1 [c][k=192] bf16 ----------------

__global__ __launch_bounds__(256) void prep_w_kernel(const float* __restrict__ W1,
                                                     const float* __restrict__ W2,
                                                     const float* __restrict__ Wp1,
                                                     ushort_t* __restrict__ Wt1,
                                                     ushort_t* __restrict__ Wt2,
                                                     ushort_t* __restrict__ Wtp1) {
    int g = blockIdx.x * 256 + threadIdx.x;   // granule id
    if (g < 2048) {           // W1: g = k8*128 + c
        int c = g & 127, k8 = g >> 7;
        ushort8v o;
#pragma unroll
        for (int j = 0; j < 8; j++) o[j] = f2bf(W1[(size_t)(k8 * 8 + j) * 128 + c]);
        *(ushort8v*)&Wt1[(size_t)c * 128 + k8 * 8] = o;
    } else if (g < 3072) {    // W2: g2 = k8*64 + c
        int g2 = g - 2048;
        int c = g2 & 63, k8 = g2 >> 6;
        ushort8v o;
#pragma unroll
        for (int j = 0; j < 8; j++) o[j] = f2bf(W2[(size_t)(k8 * 8 + j) * 64 + c]);
        *(ushort8v*)&Wt2[(size_t)c * 128 + k8 * 8] = o;
    } else if (g < 4608) {    // Wp1: g2 = c*24 + k8  (c in 0..63, k8 in 0..23)
        int g2 = g - 3072;
        int c = g2 / 24, k8 = g2 % 24;
        ushort8v o;
#pragma unroll
        for (int j = 0; j < 8; j++) o[j] = f2bf(Wp1[(size_t)(k8 * 8 + j) * 64 + c]);
        *(ushort8v*)&Wtp1[(size_t)g2 * 8] = o;
    }
}

// ---------------- GEMM1 (MFMA): y = bf16(node_emb + type_emb[tid]) @ bf16(W1) -> bf16 chunk-major [4][N][32] ----------------

__global__ __launch_bounds__(256) void gemm1_mfma_kernel(const float* __restrict__ node_emb,
                                                         const float* __restrict__ type_emb,
                                                         const int* __restrict__ tids,
                                                         const ushort_t* __restrict__ Wt1,
                                                         ushort_t* __restrict__ y, int n) {
    __shared__ __align__(16) ushort_t As[64 * 128];    // 16 KB
    __shared__ __align__(16) ushort_t Ws[128 * 128];   // 32 KB
    int t = threadIdx.x;

    for (int gi = t; gi < 2048; gi += 256) {
        int c = gi >> 4, kg = gi & 15;
        ushort8v v = *(const ushort8v*)&Wt1[gi * 8];
        *(ushort8v*)&Ws[c * 128 + ((kg ^ (c & 7)) << 3)] = v;
    }
    int row_l = t >> 2;
    int row_g = blockIdx.x * 64 + row_l;
    int kseg = (t & 3) * 32;
    if (row_g < n) {
        int tv = tids[row_g];
        const float4* na = (const float4*)(node_emb + (size_t)row_g * 128 + kseg);
        const float4* ta = (const float4*)(type_emb + (size_t)tv * 128 + kseg);
#pragma unroll
        for (int i2 = 0; i2 < 4; i2++) {
            float4 a = na[i2 * 2], b = ta[i2 * 2];
            float4 a2 = na[i2 * 2 + 1], b2 = ta[i2 * 2 + 1];
            ushort8v o;
            o[0] = f2bf(a.x + b.x);  o[1] = f2bf(a.y + b.y);
            o[2] = f2bf(a.z + b.z);  o[3] = f2bf(a.w + b.w);
            o[4] = f2bf(a2.x + b2.x); o[5] = f2bf(a2.y + b2.y);
            o[6] = f2bf(a2.z + b2.z); o[7] = f2bf(a2.w + b2.w);
            int kg = (t & 3) * 4 + i2;
            *(ushort8v*)&As[row_l * 128 + ((kg ^ (row_l & 7)) << 3)] = o;
        }
    } else {
        ushort8v z = (ushort8v)(ushort_t)0;
#pragma unroll
        for (int i2 = 0; i2 < 4; i2++) {
            int kg = (t & 3) * 4 + i2;
            *(ushort8v*)&As[row_l * 128 + ((kg ^ (row_l & 7)) << 3)] = z;
        }
    }
    __syncthreads();

    int lane = t & 63, wid = t >> 6;
    int m0 = (wid & 1) * 32, n0 = (wid >> 1) * 64;
    int lr = lane & 15, lk = lane >> 4;
    f32x4 acc[2][4] = {};
#pragma unroll
    for (int ks = 0; ks < 4; ks++) {
        int kg = ks * 4 + lk;
        bf16x8 afr[2];
#pragma unroll
        for (int mt = 0; mt < 2; mt++) {
            int r = m0 + mt * 16 + lr;
            afr[mt] = *(const bf16x8*)&As[r * 128 + ((kg ^ (r & 7)) << 3)];
        }
#pragma unroll
        for (int nt = 0; nt < 4; nt++) {
            int c = n0 + nt * 16 + lr;
            bf16x8 bfr = *(const bf16x8*)&Ws[c * 128 + ((kg ^ (c & 7)) << 3)];
            acc[0][nt] = __builtin_amdgcn_mfma_f32_16x16x32_bf16(afr[0], bfr, acc[0][nt], 0, 0, 0);
            acc[1][nt] = __builtin_amdgcn_mfma_f32_16x16x32_bf16(afr[1], bfr, acc[1][nt], 0, 0, 0);
        }
    }
    // epilogue: chunk-major write y[(c>>5)][rg][c&31]
#pragma unroll
    for (int mt = 0; mt < 2; mt++) {
#pragma unroll
        for (int j = 0; j < 4; j++) {
            int rg = blockIdx.x * 64 + m0 + mt * 16 + lk * 4 + j;
            if (rg < n) {
#pragma unroll
                for (int nt = 0; nt < 4; nt++) {
                    int c = n0 + nt * 16 + lr;
                    y[((size_t)(c >> 5) * n + rg) * 32 + (c & 31)] = f2bf(acc[mt][nt][j]);
                }
            }
        }
    }
}

// ---------------- GEMM2 (MFMA): g = h(bf16 chunk-major [4][N][32]) @ bf16(W2) -> bf16 chunk-major [2][N][32] ----------------

__global__ __launch_bounds__(256) void gemm2_mfma_kernel(const ushort_t* __restrict__ h,
                                                         const ushort_t* __restrict__ Wt2,
                                                         ushort_t* __restrict__ g, int n) {
    __shared__ __align__(16) ushort_t As[64 * 128];    // 16 KB
    __shared__ __align__(16) ushort_t Ws[64 * 128];    // 16 KB
    int t = threadIdx.x;

    for (int gi = t; gi < 1024; gi += 256) {
        int c = gi >> 4, kg = gi & 15;
        ushort8v v = *(const ushort8v*)&Wt2[gi * 8];
        *(ushort8v*)&Ws[c * 128 + ((kg ^ (c & 7)) << 3)] = v;
    }
    int row_l = t >> 2;
    int row_g = blockIdx.x * 64 + row_l;
    int ch = t & 3;
    if (row_g < n) {
        const ushort8v* hr = (const ushort8v*)(h + ((size_t)ch * n + row_g) * 32);
#pragma unroll
        for (int i2 = 0; i2 < 4; i2++) {
            ushort8v v = hr[i2];
            int kg = ch * 4 + i2;
            *(ushort8v*)&As[row_l * 128 + ((kg ^ (row_l & 7)) << 3)] = v;
        }
    } else {
        ushort8v z = (ushort8v)(ushort_t)0;
#pragma unroll
        for (int i2 = 0; i2 < 4; i2++) {
            int kg = ch * 4 + i2;
            *(ushort8v*)&As[row_l * 128 + ((kg ^ (row_l & 7)) << 3)] = z;
        }
    }
    __syncthreads();

    int lane = t & 63, wid = t >> 6;
    int m0 = (wid & 1) * 32, n0 = (wid >> 1) * 32;
    int lr = lane & 15, lk = lane >> 4;
    f32x4 acc[2][2] = {};
#pragma unroll
    for (int ks = 0; ks < 4; ks++) {
        int kg = ks * 4 + lk;
        bf16x8 afr[2];
#pragma unroll
        for (int mt = 0; mt < 2; mt++) {
            int r = m0 + mt * 16 + lr;
            afr[mt] = *(const bf16x8*)&As[r * 128 + ((kg ^ (r & 7)) << 3)];
        }
#pragma unroll
        for (int nt = 0; nt < 2; nt++) {
            int c = n0 + nt * 16 + lr;
            bf16x8 bfr = *(const bf16x8*)&Ws[c * 128 + ((kg ^ (c & 7)) << 3)];
            acc[0][nt] = __builtin_amdgcn_mfma_f32_16x16x32_bf16(afr[0], bfr, acc[0][nt], 0, 0, 0);
            acc[1][nt] = __builtin_amdgcn_mfma_f32_16x16x32_bf16(afr[1], bfr, acc[1][nt], 0, 0, 0);
        }
    }
#pragma unroll
    for (int mt = 0; mt < 2; mt++) {
#pragma unroll
        for (int j = 0; j < 4; j++) {
            int rg = blockIdx.x * 64 + m0 + mt * 16 + lk * 4 + j;
            if (rg < n) {
#pragma unroll
                for (int nt = 0; nt < 2; nt++) {
                    int c = n0 + nt * 16 + lr;
                    g[((size_t)(c >> 5) * n + rg) * 32 + (c & 31)] = f2bf(acc[mt][nt][j]);
                }
            }
        }
    }
}

// ---------------- SpMM v5: chunked v4. 4-lane group per (row,chunk), 8 cols/lane, no reduction. ----------------
// Table chunk-major [NCHUNK][n][32]; chunk = blockIdx & (NCHUNK-1) -> round-robin XCD gets one chunk slice
// (3.2 MB, L2-resident). Per-lane work identical to v4 (deg x (shfl+load+8FMA)) -> no VALU overhead added.

template <int NCHUNK, bool RELU, bool BF16OUT>
__global__ __launch_bounds__(256) void spmm_v5_kernel(const int* __restrict__ row_ptr,
                                                      const uint_t* __restrict__ csr_edge,
                                                      const ushort_t* __restrict__ src_base,
                                                      const float* __restrict__ bias,
                                                      void* __restrict__ dst, int n) {
    constexpr int SH = (NCHUNK == 4) ? 2 : 1;
    int ch = blockIdx.x & (NCHUNK - 1);
    int rowblk = blockIdx.x >> SH;
    int t = threadIdx.x;
    int lane = t & 63, wid = t >> 6;
    int gl = lane & 3;            // lane within 4-lane group
    int gbase = lane & ~3;        // first lane of group
    int row = rowblk * 64 + wid * 16 + (lane >> 2);
    int c8 = gl * 8;
    if (row >= n) return;
    const ushort_t* src = src_base + (size_t)ch * n * 32;
    int start = row_ptr[row], end = row_ptr[row + 1];

    float acc[8] = {};
    for (int base = start; base < end; base += 4) {
        int idx = base + gl;
        uint_t pe = (idx < end) ? csr_edge[idx] : 0u;
        int cnt = min(4, end - base);
        for (int j = 0; j < cnt; j++) {
            uint_t p = (uint_t)__shfl((int)pe, gbase + j);
            int cc = p & 0xFFFF;
            float vv = bf2f((ushort_t)(p >> 16));
            const ushort8v s = *(const ushort8v*)(src + (size_t)cc * 32 + c8);
#pragma unroll
            for (int m = 0; m < 8; m++) acc[m] += vv * bf2f(s[m]);
        }
    }
    int cg = ch * 32 + c8;
#pragma unroll
    for (int m = 0; m < 8; m++) {
        acc[m] += bias[cg + m];
        if (RELU) acc[m] = fmaxf(acc[m], 0.f);
    }
    if (BF16OUT) {
        ushort8v o;
#pragma unroll
        for (int m = 0; m < 8; m++) o[m] = f2bf(acc[m]);
        *(ushort8v*)((ushort_t*)dst + ((size_t)ch * n + row) * 32 + c8) = o;
    } else {
        float4 o0 = make_float4(acc[0], acc[1], acc[2], acc[3]);
        float4 o1 = make_float4(acc[4], acc[5], acc[6], acc[7]);
        *(float4*)((float*)dst + (size_t)row * (NCHUNK * 32) + cg) = o0;
        *(float4*)((float*)dst + (size_t)row * (NCHUNK * 32) + cg + 4) = o1;
    }
}

// ---------------- Pair scorer (MFMA): feat[64,192](bf16) @ Wp1(bf16) -> relu -> @Wp2 (f32) ----------------

__global__ __launch_bounds__(256) void pair_mfma_kernel(const int* __restrict__ pairs,
                                                        const float* __restrict__ z,
                                                        const ushort_t* __restrict__ Wtp1,
                                                        const float* __restrict__ bp1,
                                                        const float* __restrict__ Wp2,
                                                        const float* __restrict__ bp2,
                                                        float* __restrict__ out) {
    __shared__ __align__(16) ushort_t Fs[64 * 192];   // 24 KB (feat, swizzled)
    __shared__ __align__(16) ushort_t Ws[64 * 192];   // 24 KB (Wp1^T, swizzled)
    int t = threadIdx.x;

    for (int gi = t; gi < 1536; gi += 256) {
        int c = gi / 24, kg = gi % 24;
        ushort8v v = *(const ushort8v*)&Wtp1[(size_t)gi * 8];
        *(ushort8v*)&Ws[c * 192 + ((kg ^ (c & 7)) << 3)] = v;
    }
    int row_l = t >> 2;
    int rg = blockIdx.x * 64 + row_l;
    int p0 = pairs[rg], p1 = pairs[NPAIRS + rg];
    const float* z0 = z + (size_t)p0 * 64;
    const float* z1 = z + (size_t)p1 * 64;
    int q = t & 3;
#pragma unroll
    for (int i = 0; i < 6; i++) {
        int kg = q * 6 + i;          // 0..23
        int k0 = kg * 8;
        float v[8];
        if (k0 < 64) {
#pragma unroll
            for (int m = 0; m < 8; m++) v[m] = z0[k0 + m];
        } else if (k0 < 128) {
#pragma unroll
            for (int m = 0; m < 8; m++) v[m] = z1[k0 - 64 + m];
        } else {
#pragma unroll
            for (int m = 0; m < 8; m++) v[m] = z0[k0 - 128 + m] * z1[k0 - 128 + m];
        }
        ushort8v o;
#pragma unroll
        for (int m = 0; m < 8; m++) o[m] = f2bf(v[m]);
        *(ushort8v*)&Fs[row_l * 192 + ((kg ^ (row_l & 7)) << 3)] = o;
    }
    __syncthreads();

    int lane = t & 63, wid = t >> 6;
    int m0 = wid * 16;
    int lr = lane & 15, lk = lane >> 4;
    f32x4 acc[4] = {};
#pragma unroll
    for (int ks = 0; ks < 6; ks++) {
        int kg = ks * 4 + lk;
        int r = m0 + lr;
        bf16x8 afr = *(const bf16x8*)&Fs[r * 192 + ((kg ^ (r & 7)) << 3)];
#pragma unroll
        for (int nt = 0; nt < 4; nt++) {
            int c = nt * 16 + lr;
            bf16x8 bfr = *(const bf16x8*)&Ws[c * 192 + ((kg ^ (c & 7)) << 3)];
            acc[nt] = __builtin_amdgcn_mfma_f32_16x16x32_bf16(afr, bfr, acc[nt], 0, 0, 0);
        }
    }
    float s[4] = {};
#pragma unroll
    for (int nt = 0; nt < 4; nt++) {
        int c = nt * 16 + lr;
        float b = bp1[c], w = Wp2[c];
#pragma unroll
        for (int j = 0; j < 4; j++) s[j] += fmaxf(acc[nt][j] + b, 0.f) * w;
    }
#pragma unroll
    for (int j = 0; j < 4; j++) {
        s[j] += __shfl_xor(s[j], 1);
        s[j] += __shfl_xor(s[j], 2);
        s[j] += __shfl_xor(s[j], 4);
        s[j] += __shfl_xor(s[j], 8);
    }
    if (lr == 0) {
        float bb = bp2[0];
#pragma unroll
        for (int j = 0; j < 4; j++)
            out[blockIdx.x * 64 + m0 + lk * 4 + j] = s[j] + bb;
    }
}

// ---------------- launch ----------------

extern "C" void kernel_launch(void* const* d_in, const int* in_sizes, int n_in,
                              void* d_out, int out_size, void* d_ws, size_t ws_size,
                              hipStream_t stream) {
    const int*   tids     = (const int*)d_in[0];
    const int*   adj_rows = (const int*)d_in[1];
    const int*   adj_cols = (const int*)d_in[2];
    const float* adj_vals = (const float*)d_in[3];
    const int*   pairs    = (const int*)d_in[4];
    const float* node_emb = (const float*)d_in[5];
    const float* type_emb = (const float*)d_in[6];
    const float* W1  = (const float*)d_in[7];
    const float* b1  = (const float*)d_in[8];
    const float* W2  = (const float*)d_in[9];
    const float* b2  = (const float*)d_in[10];
    const float* Wp1 = (const float*)d_in[11];
    const float* bp1 = (const float*)d_in[12];
    const float* Wp2 = (const float*)d_in[13];
    const float* bp2 = (const float*)d_in[14];
    float* out = (float*)d_out;

    int n = in_sizes[0];
    int e = in_sizes[1];
    int p = in_sizes[4] / 2;

    char* ws = (char*)d_ws;
    // region A (12.8 MB): tmpA u64[e] -> y bf16 chunk-major [4][n][32] -> g bf16 chunk-major [2][n][32]
    ushort_t* bufY = (ushort_t*)ws;
    u64_t* tmpA = (u64_t*)ws;
    // region B (12.8 MB): tmpB u64[e] -> h bf16 chunk-major [4][n][32] -> z f32 [n,64]
    char* wsB = ws + (size_t)n * 128 * sizeof(ushort_t);
    ushort_t* bufH = (ushort_t*)wsB;
    float* bufZ = (float*)wsB;
    u64_t* tmpB = (u64_t*)wsB;

    int* row_ptr   = (int*)(wsB + (size_t)n * 128 * sizeof(ushort_t));  // n+1
    int* blockhist = row_ptr + (n + 1);                   // NBUCK*RBLOCKS
    int L  = NBUCK * RBLOCKS;                             // 152881
    int* blksum1   = blockhist + L;                       // <=1024
    uint_t* csr_edge = (uint_t*)(blksum1 + 1024);         // e (packed u32)
    ushort_t* Wt1 = (ushort_t*)(csr_edge + e);            // 128*128 bf16
    ushort_t* Wt2 = Wt1 + 128 * 128;                      // 64*128 bf16
    ushort_t* Wtp1 = Wt2 + 64 * 128;                      // 64*192 bf16

    int SG = (L + 255) / 256;                             // 598

    prep_w_kernel<<<18, 256, 0, stream>>>(W1, W2, Wp1, Wt1, Wt2, Wtp1);
    pack_hist_kernel<<<RBLOCKS, 256, 0, stream>>>(adj_rows, adj_cols, adj_vals, tmpA, blockhist, e);
    scan_block_kernel<<<SG, 256, 0, stream>>>(blockhist, blockhist, blksum1, L);
    scan_mid_kernel<<<1, 256, 0, stream>>>(blksum1, SG);
    scan_add2_kernel<<<SG, 256, 0, stream>>>(blockhist, blksum1, L);
    radix_scatter_kernel<<<RBLOCKS, 256, 0, stream>>>(tmpA, blockhist, tmpB, e);
    bucket_sort_kernel<<<NBUCK, 256, 0, stream>>>(tmpB, blockhist, csr_edge, row_ptr, e, n);

    int rb = (n + 63) / 64;
    gemm1_mfma_kernel<<<rb, 256, 0, stream>>>(node_emb, type_emb, tids, Wt1, bufY, n);
    spmm_v5_kernel<4, true, true><<<rb * 4, 256, 0, stream>>>(row_ptr, csr_edge, bufY, b1, bufH, n);
    gemm2_mfma_kernel<<<rb, 256, 0, stream>>>(bufH, Wt2, bufY, n);   // g -> region A
    spmm_v5_kernel<2, false, false><<<rb * 2, 256, 0, stream>>>(row_ptr, csr_edge, bufY, b2, bufZ, n);
    pair_mfma_kernel<<<p / 64, 256, 0, stream>>>(pairs, bufZ, Wtp1, bp1, Wp2, bp2, out);
}

// Round 20
// 138.132 us; speedup vs baseline: 1.0493x; 1.0493x over previous
//
#include <hip/hip_runtime.h>

#define N_NODES 50000
#define N_EDGES 800000
#define NPAIRS  65536

#define NBUCK 391          // ceil(N_NODES/128): coarse bucket = row>>7
#define RTILE 2048
#define RBLOCKS 391        // ceil(N_EDGES/RTILE)

typedef unsigned short ushort_t;
typedef unsigned int uint_t;
typedef unsigned long long u64_t;
typedef ushort_t ushort8v __attribute__((ext_vector_type(8)));
typedef short bf16x8 __attribute__((ext_vector_type(8)));
typedef float f32x4 __attribute__((ext_vector_type(4)));

__device__ inline ushort_t f2bf(float f) {
    uint_t u = __float_as_uint(f);
    u = (u + 0x7FFF + ((u >> 16) & 1)) >> 16;   // RTN-even
    return (ushort_t)u;
}
__device__ inline float bf2f(ushort_t b) {
    return __uint_as_float(((uint_t)b) << 16);
}

// ---------------- CSR build: block-staged bucket sort ----------------

__global__ __launch_bounds__(256) void pack_hist_kernel(const int* __restrict__ rows,
                                                        const int* __restrict__ cols,
                                                        const float* __restrict__ vals,
                                                        u64_t* __restrict__ tmpA,
                                                        int* __restrict__ blockhist, int e) {
    __shared__ int lh[NBUCK];
    int blk = blockIdx.x, t = threadIdx.x;
    for (int i = t; i < NBUCK; i += 256) lh[i] = 0;
    __syncthreads();
    int base = blk * RTILE;
#pragma unroll
    for (int k = 0; k < RTILE / 256; k++) {
        int idx = base + k * 256 + t;
        if (idx < e) {
            int r = rows[idx];
            uint_t payload = (uint_t)cols[idx] | ((uint_t)f2bf(vals[idx]) << 16);
            tmpA[idx] = ((u64_t)r << 32) | payload;
            atomicAdd(&lh[r >> 7], 1);
        }
    }
    __syncthreads();
    for (int d = t; d < NBUCK; d += 256) blockhist[d * RBLOCKS + blk] = lh[d];
}

__global__ __launch_bounds__(256) void scan_block_kernel(const int* __restrict__ cnt,
                                                         int* __restrict__ excl,
                                                         int* __restrict__ blksum, int n) {
    __shared__ int s[256];
    int tid = threadIdx.x;
    int i = blockIdx.x * 256 + tid;
    int v = (i < n) ? cnt[i] : 0;
    s[tid] = v; __syncthreads();
    for (int off = 1; off < 256; off <<= 1) {
        int t = (tid >= off) ? s[tid - off] : 0;
        __syncthreads();
        s[tid] += t;
        __syncthreads();
    }
    if (i < n) excl[i] = s[tid] - v;
    if (tid == 255) blksum[blockIdx.x] = s[255];
}

// single-block multi-chunk exclusive scan (in place)
__global__ __launch_bounds__(256) void scan_mid_kernel(int* __restrict__ data, int n) {
    __shared__ int s[256];
    __shared__ int carry;
    int t = threadIdx.x;
    if (t == 0) carry = 0;
    __syncthreads();
    for (int base = 0; base < n; base += 256) {
        int i = base + t;
        int v = (i < n) ? data[i] : 0;
        s[t] = v; __syncthreads();
        for (int off = 1; off < 256; off <<= 1) {
            int x = (t >= off) ? s[t - off] : 0;
            __syncthreads();
            s[t] += x;
            __syncthreads();
        }
        int excl = s[t] - v + carry;
        if (i < n) data[i] = excl;
        __syncthreads();
        if (t == 255) carry += s[255];
        __syncthreads();
    }
}

__global__ __launch_bounds__(256) void scan_add2_kernel(int* __restrict__ data,
                                                        const int* __restrict__ blksum, int n) {
    int i = blockIdx.x * 256 + threadIdx.x;
    if (i < n) data[i] += blksum[blockIdx.x];
}

__global__ __launch_bounds__(256) void radix_scatter_kernel(const u64_t* __restrict__ tmpA,
                                                            const int* __restrict__ gofs,
                                                            u64_t* __restrict__ tmpB, int e) {
    __shared__ u64_t stage[RTILE];          // 16 KB
    __shared__ int lh[NBUCK];
    __shared__ int lstart[NBUCK];
    __shared__ int lcur[NBUCK];
    int blk = blockIdx.x, t = threadIdx.x;
    for (int i = t; i < NBUCK; i += 256) lh[i] = 0;
    __syncthreads();
    int base = blk * RTILE;
    int cnt = min(RTILE, e - base);
    for (int k = t; k < cnt; k += 256) {
        int d = (int)(tmpA[base + k] >> 39);   // (row>>7)
        atomicAdd(&lh[d], 1);
    }
    __syncthreads();
    if (t == 0) {
        int s = 0;
        for (int d = 0; d < NBUCK; d++) { lstart[d] = s; s += lh[d]; }
    }
    __syncthreads();
    for (int i = t; i < NBUCK; i += 256) lcur[i] = lstart[i];
    __syncthreads();
    for (int k = t; k < cnt; k += 256) {
        u64_t it = tmpA[base + k];
        int d = (int)(it >> 39);
        int slot = atomicAdd(&lcur[d], 1);
        stage[slot] = it;
    }
    __syncthreads();
    for (int k = t; k < cnt; k += 256) {
        u64_t it = stage[k];
        int d = (int)(it >> 39);
        tmpB[gofs[d * RBLOCKS + blk] + (k - lstart[d])] = it;
    }
}

__global__ __launch_bounds__(256) void bucket_sort_kernel(const u64_t* __restrict__ tmpB,
                                                          const int* __restrict__ gofs,
                                                          uint_t* __restrict__ csr_edge,
                                                          int* __restrict__ row_ptr, int e, int n) {
    __shared__ uint_t stage[4096];
    __shared__ int lh[128];
    __shared__ int lstart[128];
    __shared__ int lcur[128];
    int d = blockIdx.x, t = threadIdx.x;
    int bstart = gofs[d * RBLOCKS];
    int bend = (d == NBUCK - 1) ? e : gofs[(d + 1) * RBLOCKS];
    int len = bend - bstart;
    for (int i = t; i < 128; i += 256) lh[i] = 0;
    __syncthreads();
    for (int k = t; k < len; k += 256) {
        int lr = (int)((tmpB[bstart + k] >> 32) & 127);
        atomicAdd(&lh[lr], 1);
    }
    __syncthreads();
    if (t == 0) {
        int s = 0;
        for (int j = 0; j < 128; j++) { lstart[j] = s; s += lh[j]; }
    }
    __syncthreads();
    if (t < 128) {
        int grow = d * 128 + t;
        if (grow <= n) row_ptr[grow] = bstart + lstart[t];
    }
    for (int i = t; i < 128; i += 256) lcur[i] = lstart[i];
    __syncthreads();
    for (int k = t; k < len; k += 256) {
        u64_t it = tmpB[bstart + k];
        int lr = (int)((it >> 32) & 127);
        int slot = atomicAdd(&lcur[lr], 1);
        stage[slot] = (uint_t)it;
    }
    __syncthreads();
    for (int k = t; k < len; k += 256) csr_edge[bstart + k] = stage[k];
}

// ---------------- W prep: Wt1 [c][k] bf16, Wt2 [c][k] bf16, Wtp1 [c][k=192] bf16 ----------------

__global__ __launch_bounds__(256) void prep_w_kernel(const float* __restrict__ W1,
                                                     const float* __restrict__ W2,
                                                     const float* __restrict__ Wp1,
                                                     ushort_t* __restrict__ Wt1,
                                                     ushort_t* __restrict__ Wt2,
                                                     ushort_t* __restrict__ Wtp1) {
    int g = blockIdx.x * 256 + threadIdx.x;   // granule id
    if (g < 2048) {           // W1: g = k8*128 + c
        int c = g & 127, k8 = g >> 7;
        ushort8v o;
#pragma unroll
        for (int j = 0; j < 8; j++) o[j] = f2bf(W1[(size_t)(k8 * 8 + j) * 128 + c]);
        *(ushort8v*)&Wt1[(size_t)c * 128 + k8 * 8] = o;
    } else if (g < 3072) {    // W2: g2 = k8*64 + c
        int g2 = g - 2048;
        int c = g2 & 63, k8 = g2 >> 6;
        ushort8v o;
#pragma unroll
        for (int j = 0; j < 8; j++) o[j] = f2bf(W2[(size_t)(k8 * 8 + j) * 64 + c]);
        *(ushort8v*)&Wt2[(size_t)c * 128 + k8 * 8] = o;
    } else if (g < 4608) {    // Wp1: g2 = c*24 + k8  (c in 0..63, k8 in 0..23)
        int g2 = g - 3072;
        int c = g2 / 24, k8 = g2 % 24;
        ushort8v o;
#pragma unroll
        for (int j = 0; j < 8; j++) o[j] = f2bf(Wp1[(size_t)(k8 * 8 + j) * 64 + c]);
        *(ushort8v*)&Wtp1[(size_t)g2 * 8] = o;
    }
}

// ---------------- GEMM1 (MFMA): y = bf16(node_emb + type_emb[tid]) @ bf16(W1) -> bf16 [N,128] ----------------

__global__ __launch_bounds__(256) void gemm1_mfma_kernel(const float* __restrict__ node_emb,
                                                         const float* __restrict__ type_emb,
                                                         const int* __restrict__ tids,
                                                         const ushort_t* __restrict__ Wt1,
                                                         ushort_t* __restrict__ y, int n) {
    __shared__ __align__(16) ushort_t As[64 * 128];    // 16 KB
    __shared__ __align__(16) ushort_t Ws[128 * 128];   // 32 KB
    int t = threadIdx.x;

    for (int gi = t; gi < 2048; gi += 256) {
        int c = gi >> 4, kg = gi & 15;
        ushort8v v = *(const ushort8v*)&Wt1[gi * 8];
        *(ushort8v*)&Ws[c * 128 + ((kg ^ (c & 7)) << 3)] = v;
    }
    int row_l = t >> 2;
    int row_g = blockIdx.x * 64 + row_l;
    int kseg = (t & 3) * 32;
    if (row_g < n) {
        int tv = tids[row_g];
        const float4* na = (const float4*)(node_emb + (size_t)row_g * 128 + kseg);
        const float4* ta = (const float4*)(type_emb + (size_t)tv * 128 + kseg);
#pragma unroll
        for (int i2 = 0; i2 < 4; i2++) {
            float4 a = na[i2 * 2], b = ta[i2 * 2];
            float4 a2 = na[i2 * 2 + 1], b2 = ta[i2 * 2 + 1];
            ushort8v o;
            o[0] = f2bf(a.x + b.x);  o[1] = f2bf(a.y + b.y);
            o[2] = f2bf(a.z + b.z);  o[3] = f2bf(a.w + b.w);
            o[4] = f2bf(a2.x + b2.x); o[5] = f2bf(a2.y + b2.y);
            o[6] = f2bf(a2.z + b2.z); o[7] = f2bf(a2.w + b2.w);
            int kg = (t & 3) * 4 + i2;
            *(ushort8v*)&As[row_l * 128 + ((kg ^ (row_l & 7)) << 3)] = o;
        }
    } else {
        ushort8v z = (ushort8v)(ushort_t)0;
#pragma unroll
        for (int i2 = 0; i2 < 4; i2++) {
            int kg = (t & 3) * 4 + i2;
            *(ushort8v*)&As[row_l * 128 + ((kg ^ (row_l & 7)) << 3)] = z;
        }
    }
    __syncthreads();

    int lane = t & 63, wid = t >> 6;
    int m0 = (wid & 1) * 32, n0 = (wid >> 1) * 64;
    int lr = lane & 15, lk = lane >> 4;
    f32x4 acc[2][4] = {};
#pragma unroll
    for (int ks = 0; ks < 4; ks++) {
        int kg = ks * 4 + lk;
        bf16x8 afr[2];
#pragma unroll
        for (int mt = 0; mt < 2; mt++) {
            int r = m0 + mt * 16 + lr;
            afr[mt] = *(const bf16x8*)&As[r * 128 + ((kg ^ (r & 7)) << 3)];
        }
#pragma unroll
        for (int nt = 0; nt < 4; nt++) {
            int c = n0 + nt * 16 + lr;
            bf16x8 bfr = *(const bf16x8*)&Ws[c * 128 + ((kg ^ (c & 7)) << 3)];
            acc[0][nt] = __builtin_amdgcn_mfma_f32_16x16x32_bf16(afr[0], bfr, acc[0][nt], 0, 0, 0);
            acc[1][nt] = __builtin_amdgcn_mfma_f32_16x16x32_bf16(afr[1], bfr, acc[1][nt], 0, 0, 0);
        }
    }
#pragma unroll
    for (int mt = 0; mt < 2; mt++) {
#pragma unroll
        for (int j = 0; j < 4; j++) {
            int rg = blockIdx.x * 64 + m0 + mt * 16 + lk * 4 + j;
            if (rg < n) {
#pragma unroll
                for (int nt = 0; nt < 4; nt++) {
                    int c = n0 + nt * 16 + lr;
                    y[(size_t)rg * 128 + c] = f2bf(acc[mt][nt][j]);
                }
            }
        }
    }
}

// ---------------- GEMM2 (MFMA): g = h(bf16) @ bf16(W2) -> bf16 [N,64] ----------------

__global__ __launch_bounds__(256) void gemm2_mfma_kernel(const ushort_t* __restrict__ h,
                                                         const ushort_t* __restrict__ Wt2,
                                                         ushort_t* __restrict__ g, int n) {
    __shared__ __align__(16) ushort_t As[64 * 128];    // 16 KB
    __shared__ __align__(16) ushort_t Ws[64 * 128];    // 16 KB
    int t = threadIdx.x;

    for (int gi = t; gi < 1024; gi += 256) {
        int c = gi >> 4, kg = gi & 15;
        ushort8v v = *(const ushort8v*)&Wt2[gi * 8];
        *(ushort8v*)&Ws[c * 128 + ((kg ^ (c & 7)) << 3)] = v;
    }
    int row_l = t >> 2;
    int row_g = blockIdx.x * 64 + row_l;
    int kseg = (t & 3) * 32;
    if (row_g < n) {
        const ushort8v* hr = (const ushort8v*)(h + (size_t)row_g * 128 + kseg);
#pragma unroll
        for (int i2 = 0; i2 < 4; i2++) {
            ushort8v v = hr[i2];
            int kg = (t & 3) * 4 + i2;
            *(ushort8v*)&As[row_l * 128 + ((kg ^ (row_l & 7)) << 3)] = v;
        }
    } else {
        ushort8v z = (ushort8v)(ushort_t)0;
#pragma unroll
        for (int i2 = 0; i2 < 4; i2++) {
            int kg = (t & 3) * 4 + i2;
            *(ushort8v*)&As[row_l * 128 + ((kg ^ (row_l & 7)) << 3)] = z;
        }
    }
    __syncthreads();

    int lane = t & 63, wid = t >> 6;
    int m0 = (wid & 1) * 32, n0 = (wid >> 1) * 32;
    int lr = lane & 15, lk = lane >> 4;
    f32x4 acc[2][2] = {};
#pragma unroll
    for (int ks = 0; ks < 4; ks++) {
        int kg = ks * 4 + lk;
        bf16x8 afr[2];
#pragma unroll
        for (int mt = 0; mt < 2; mt++) {
            int r = m0 + mt * 16 + lr;
            afr[mt] = *(const bf16x8*)&As[r * 128 + ((kg ^ (r & 7)) << 3)];
        }
#pragma unroll
        for (int nt = 0; nt < 2; nt++) {
            int c = n0 + nt * 16 + lr;
            bf16x8 bfr = *(const bf16x8*)&Ws[c * 128 + ((kg ^ (c & 7)) << 3)];
            acc[0][nt] = __builtin_amdgcn_mfma_f32_16x16x32_bf16(afr[0], bfr, acc[0][nt], 0, 0, 0);
            acc[1][nt] = __builtin_amdgcn_mfma_f32_16x16x32_bf16(afr[1], bfr, acc[1][nt], 0, 0, 0);
        }
    }
#pragma unroll
    for (int mt = 0; mt < 2; mt++) {
#pragma unroll
        for (int j = 0; j < 4; j++) {
            int rg = blockIdx.x * 64 + m0 + mt * 16 + lk * 4 + j;
            if (rg < n) {
#pragma unroll
                for (int nt = 0; nt < 2; nt++) {
                    int c = n0 + nt * 16 + lr;
                    g[(size_t)rg * 64 + c] = f2bf(acc[mt][nt][j]);
                }
            }
        }
    }
}

// ---------------- SpMM v6: v4 + 4-wide edge unroll (4 independent gathers in flight) ----------------
// One F/8-lane group per row, 8 cols/lane, no cross-lane reduction. Accumulation order per column
// identical to v4 (j, j+1, j+2, j+3 sequential) -> bit-identical output.

template <int F, bool RELU, bool BF16OUT>
__global__ __launch_bounds__(256) void spmm_v6_kernel(const int* __restrict__ row_ptr,
                                                      const uint_t* __restrict__ csr_edge,
                                                      const ushort_t* __restrict__ src,
                                                      const float* __restrict__ bias,
                                                      void* __restrict__ dst, int n) {
    constexpr int GL = F / 8;           // lanes per group (16 or 8)
    constexpr int RPB = (64 / GL) * 4;  // rows per block (16 or 32)
    int t = threadIdx.x;
    int lane = t & 63, wid = t >> 6;
    int gl = lane % GL;                 // lane within group
    int gbase = lane - gl;              // first lane of group
    int row = blockIdx.x * RPB + wid * (64 / GL) + (lane / GL);
    int c8 = gl * 8;
    if (row >= n) return;
    int start = row_ptr[row], end = row_ptr[row + 1];

    float acc[8] = {};
    for (int base = start; base < end; base += GL) {
        int idx = base + gl;
        uint_t pe = (idx < end) ? csr_edge[idx] : 0u;
        int cnt = min(GL, end - base);
        int j = 0;
        for (; j + 4 <= cnt; j += 4) {
            uint_t p0 = (uint_t)__shfl((int)pe, gbase + j);
            uint_t p1 = (uint_t)__shfl((int)pe, gbase + j + 1);
            uint_t p2 = (uint_t)__shfl((int)pe, gbase + j + 2);
            uint_t p3 = (uint_t)__shfl((int)pe, gbase + j + 3);
            const ushort8v s0 = *(const ushort8v*)(src + (size_t)(p0 & 0xFFFF) * F + c8);
            const ushort8v s1 = *(const ushort8v*)(src + (size_t)(p1 & 0xFFFF) * F + c8);
            const ushort8v s2 = *(const ushort8v*)(src + (size_t)(p2 & 0xFFFF) * F + c8);
            const ushort8v s3 = *(const ushort8v*)(src + (size_t)(p3 & 0xFFFF) * F + c8);
            float v0 = bf2f((ushort_t)(p0 >> 16));
            float v1 = bf2f((ushort_t)(p1 >> 16));
            float v2 = bf2f((ushort_t)(p2 >> 16));
            float v3 = bf2f((ushort_t)(p3 >> 16));
#pragma unroll
            for (int m = 0; m < 8; m++) {
                acc[m] += v0 * bf2f(s0[m]);
                acc[m] += v1 * bf2f(s1[m]);
                acc[m] += v2 * bf2f(s2[m]);
                acc[m] += v3 * bf2f(s3[m]);
            }
        }
        for (; j < cnt; j++) {
            uint_t p = (uint_t)__shfl((int)pe, gbase + j);
            int cc = p & 0xFFFF;
            float vv = bf2f((ushort_t)(p >> 16));
            const ushort8v s = *(const ushort8v*)(src + (size_t)cc * F + c8);
#pragma unroll
            for (int m = 0; m < 8; m++) acc[m] += vv * bf2f(s[m]);
        }
    }
#pragma unroll
    for (int m = 0; m < 8; m++) {
        acc[m] += bias[c8 + m];
        if (RELU) acc[m] = fmaxf(acc[m], 0.f);
    }
    if (BF16OUT) {
        ushort8v o;
#pragma unroll
        for (int m = 0; m < 8; m++) o[m] = f2bf(acc[m]);
        *(ushort8v*)((ushort_t*)dst + (size_t)row * F + c8) = o;
    } else {
        float4 o0 = make_float4(acc[0], acc[1], acc[2], acc[3]);
        float4 o1 = make_float4(acc[4], acc[5], acc[6], acc[7]);
        *(float4*)((float*)dst + (size_t)row * F + c8) = o0;
        *(float4*)((float*)dst + (size_t)row * F + c8 + 4) = o1;
    }
}

// ---------------- Pair scorer (MFMA): feat[64,192](bf16) @ Wp1(bf16) -> relu -> @Wp2 (f32) ----------------

__global__ __launch_bounds__(256) void pair_mfma_kernel(const int* __restrict__ pairs,
                                                        const float* __restrict__ z,
                                                        const ushort_t* __restrict__ Wtp1,
                                                        const float* __restrict__ bp1,
                                                        const float* __restrict__ Wp2,
                                                        const float* __restrict__ bp2,
                                                        float* __restrict__ out) {
    __shared__ __align__(16) ushort_t Fs[64 * 192];   // 24 KB (feat, swizzled)
    __shared__ __align__(16) ushort_t Ws[64 * 192];   // 24 KB (Wp1^T, swizzled)
    int t = threadIdx.x;

    for (int gi = t; gi < 1536; gi += 256) {
        int c = gi / 24, kg = gi % 24;
        ushort8v v = *(const ushort8v*)&Wtp1[(size_t)gi * 8];
        *(ushort8v*)&Ws[c * 192 + ((kg ^ (c & 7)) << 3)] = v;
    }
    int row_l = t >> 2;
    int rg = blockIdx.x * 64 + row_l;
    int p0 = pairs[rg], p1 = pairs[NPAIRS + rg];
    const float* z0 = z + (size_t)p0 * 64;
    const float* z1 = z + (size_t)p1 * 64;
    int q = t & 3;
#pragma unroll
    for (int i = 0; i < 6; i++) {
        int kg = q * 6 + i;          // 0..23
        int k0 = kg * 8;
        float v[8];
        if (k0 < 64) {
#pragma unroll
            for (int m = 0; m < 8; m++) v[m] = z0[k0 + m];
        } else if (k0 < 128) {
#pragma unroll
            for (int m = 0; m < 8; m++) v[m] = z1[k0 - 64 + m];
        } else {
#pragma unroll
            for (int m = 0; m < 8; m++) v[m] = z0[k0 - 128 + m] * z1[k0 - 128 + m];
        }
        ushort8v o;
#pragma unroll
        for (int m = 0; m < 8; m++) o[m] = f2bf(v[m]);
        *(ushort8v*)&Fs[row_l * 192 + ((kg ^ (row_l & 7)) << 3)] = o;
    }
    __syncthreads();

    int lane = t & 63, wid = t >> 6;
    int m0 = wid * 16;
    int lr = lane & 15, lk = lane >> 4;
    f32x4 acc[4] = {};
#pragma unroll
    for (int ks = 0; ks < 6; ks++) {
        int kg = ks * 4 + lk;
        int r = m0 + lr;
        bf16x8 afr = *(const bf16x8*)&Fs[r * 192 + ((kg ^ (r & 7)) << 3)];
#pragma unroll
        for (int nt = 0; nt < 4; nt++) {
            int c = nt * 16 + lr;
            bf16x8 bfr = *(const bf16x8*)&Ws[c * 192 + ((kg ^ (c & 7)) << 3)];
            acc[nt] = __builtin_amdgcn_mfma_f32_16x16x32_bf16(afr, bfr, acc[nt], 0, 0, 0);
        }
    }
    float s[4] = {};
#pragma unroll
    for (int nt = 0; nt < 4; nt++) {
        int c = nt * 16 + lr;
        float b = bp1[c], w = Wp2[c];
#pragma unroll
        for (int j = 0; j < 4; j++) s[j] += fmaxf(acc[nt][j] + b, 0.f) * w;
    }
#pragma unroll
    for (int j = 0; j < 4; j++) {
        s[j] += __shfl_xor(s[j], 1);
        s[j] += __shfl_xor(s[j], 2);
        s[j] += __shfl_xor(s[j], 4);
        s[j] += __shfl_xor(s[j], 8);
    }
    if (lr == 0) {
        float bb = bp2[0];
#pragma unroll
        for (int j = 0; j < 4; j++)
            out[blockIdx.x * 64 + m0 + lk * 4 + j] = s[j] + bb;
    }
}

// ---------------- launch ----------------

extern "C" void kernel_launch(void* const* d_in, const int* in_sizes, int n_in,
                              void* d_out, int out_size, void* d_ws, size_t ws_size,
                              hipStream_t stream) {
    const int*   tids     = (const int*)d_in[0];
    const int*   adj_rows = (const int*)d_in[1];
    const int*   adj_cols = (const int*)d_in[2];
    const float* adj_vals = (const float*)d_in[3];
    const int*   pairs    = (const int*)d_in[4];
    const float* node_emb = (const float*)d_in[5];
    const float* type_emb = (const float*)d_in[6];
    const float* W1  = (const float*)d_in[7];
    const float* b1  = (const float*)d_in[8];
    const float* W2  = (const float*)d_in[9];
    const float* b2  = (const float*)d_in[10];
    const float* Wp1 = (const float*)d_in[11];
    const float* bp1 = (const float*)d_in[12];
    const float* Wp2 = (const float*)d_in[13];
    const float* bp2 = (const float*)d_in[14];
    float* out = (float*)d_out;

    int n = in_sizes[0];
    int e = in_sizes[1];
    int p = in_sizes[4] / 2;

    char* ws = (char*)d_ws;
    // region A (12.8 MB): tmpA u64[e] -> y bf16 [n,128] -> g bf16 [n,64]
    ushort_t* bufY = (ushort_t*)ws;
    u64_t* tmpA = (u64_t*)ws;
    // region B (12.8 MB): tmpB u64[e] -> h bf16 [n,128] -> z f32 [n,64]
    char* wsB = ws + (size_t)n * 128 * sizeof(ushort_t);
    ushort_t* bufH = (ushort_t*)wsB;
    float* bufZ = (float*)wsB;
    u64_t* tmpB = (u64_t*)wsB;

    int* row_ptr   = (int*)(wsB + (size_t)n * 128 * sizeof(ushort_t));  // n+1
    int* blockhist = row_ptr + (n + 1);                   // NBUCK*RBLOCKS
    int L  = NBUCK * RBLOCKS;                             // 152881
    int* blksum1   = blockhist + L;                       // <=1024
    uint_t* csr_edge = (uint_t*)(blksum1 + 1024);         // e (packed u32)
    ushort_t* Wt1 = (ushort_t*)(csr_edge + e);            // 128*128 bf16
    ushort_t* Wt2 = Wt1 + 128 * 128;                      // 64*128 bf16
    ushort_t* Wtp1 = Wt2 + 64 * 128;                      // 64*192 bf16

    int SG = (L + 255) / 256;                             // 598

    prep_w_kernel<<<18, 256, 0, stream>>>(W1, W2, Wp1, Wt1, Wt2, Wtp1);
    pack_hist_kernel<<<RBLOCKS, 256, 0, stream>>>(adj_rows, adj_cols, adj_vals, tmpA, blockhist, e);
    scan_block_kernel<<<SG, 256, 0, stream>>>(blockhist, blockhist, blksum1, L);
    scan_mid_kernel<<<1, 256, 0, stream>>>(blksum1, SG);
    scan_add2_kernel<<<SG, 256, 0, stream>>>(blockhist, blksum1, L);
    radix_scatter_kernel<<<RBLOCKS, 256, 0, stream>>>(tmpA, blockhist, tmpB, e);
    bucket_sort_kernel<<<NBUCK, 256, 0, stream>>>(tmpB, blockhist, csr_edge, row_ptr, e, n);

    gemm1_mfma_kernel<<<(n + 63) / 64, 256, 0, stream>>>(node_emb, type_emb, tids, Wt1, bufY, n);
    spmm_v6_kernel<128, true, true><<<(n + 15) / 16, 256, 0, stream>>>(row_ptr, csr_edge, bufY, b1, bufH, n);
    gemm2_mfma_kernel<<<(n + 63) / 64, 256, 0, stream>>>(bufH, Wt2, bufY, n);   // g -> region A
    spmm_v6_kernel<64, false, false><<<(n + 31) / 32, 256, 0, stream>>>(row_ptr, csr_edge, bufY, b2, bufZ, n);
    pair_mfma_kernel<<<p / 64, 256, 0, stream>>>(pairs, bufZ, Wtp1, bp1, Wp2, bp2, out);
}

// Round 21
// 134.564 us; speedup vs baseline: 1.0771x; 1.0265x over previous
//
#include <hip/hip_runtime.h>

#define N_NODES 50000
#define N_EDGES 800000
#define NPAIRS  65536

#define NBUCK 391          // ceil(N_NODES/128): coarse bucket = row>>7
#define RTILE 2048
#define RBLOCKS 391        // ceil(N_EDGES/RTILE)

typedef unsigned short ushort_t;
typedef unsigned int uint_t;
typedef unsigned long long u64_t;
typedef ushort_t ushort8v __attribute__((ext_vector_type(8)));
typedef short bf16x8 __attribute__((ext_vector_type(8)));
typedef float f32x4 __attribute__((ext_vector_type(4)));

__device__ inline ushort_t f2bf(float f) {
    uint_t u = __float_as_uint(f);
    u = (u + 0x7FFF + ((u >> 16) & 1)) >> 16;   // RTN-even
    return (ushort_t)u;
}
__device__ inline float bf2f(ushort_t b) {
    return __uint_as_float(((uint_t)b) << 16);
}

// ---------------- CSR build + W prep (fused launch) ----------------
// blocks [0, RBLOCKS): pack edges + per-block bucket hist.
// blocks [RBLOCKS, RBLOCKS+18): convert/transpose W1, W2, Wp1 to bf16.

__global__ __launch_bounds__(256) void pack_hist_prep_kernel(const int* __restrict__ rows,
                                                             const int* __restrict__ cols,
                                                             const float* __restrict__ vals,
                                                             u64_t* __restrict__ tmpA,
                                                             int* __restrict__ blockhist, int e,
                                                             const float* __restrict__ W1,
                                                             const float* __restrict__ W2,
                                                             const float* __restrict__ Wp1,
                                                             ushort_t* __restrict__ Wt1,
                                                             ushort_t* __restrict__ Wt2,
                                                             ushort_t* __restrict__ Wtp1) {
    int t = threadIdx.x;
    if (blockIdx.x >= RBLOCKS) {
        int g = (blockIdx.x - RBLOCKS) * 256 + t;   // granule id, 0..4607
        if (g < 2048) {           // W1: g = k8*128 + c
            int c = g & 127, k8 = g >> 7;
            ushort8v o;
#pragma unroll
            for (int j = 0; j < 8; j++) o[j] = f2bf(W1[(size_t)(k8 * 8 + j) * 128 + c]);
            *(ushort8v*)&Wt1[(size_t)c * 128 + k8 * 8] = o;
        } else if (g < 3072) {    // W2: g2 = k8*64 + c
            int g2 = g - 2048;
            int c = g2 & 63, k8 = g2 >> 6;
            ushort8v o;
#pragma unroll
            for (int j = 0; j < 8; j++) o[j] = f2bf(W2[(size_t)(k8 * 8 + j) * 64 + c]);
            *(ushort8v*)&Wt2[(size_t)c * 128 + k8 * 8] = o;
        } else if (g < 4608) {    // Wp1: g2 = c*24 + k8
            int g2 = g - 3072;
            int c = g2 / 24, k8 = g2 % 24;
            ushort8v o;
#pragma unroll
            for (int j = 0; j < 8; j++) o[j] = f2bf(Wp1[(size_t)(k8 * 8 + j) * 64 + c]);
            *(ushort8v*)&Wtp1[(size_t)g2 * 8] = o;
        }
        return;
    }
    __shared__ int lh[NBUCK];
    int blk = blockIdx.x;
    for (int i = t; i < NBUCK; i += 256) lh[i] = 0;
    __syncthreads();
    int base = blk * RTILE;
#pragma unroll
    for (int k = 0; k < RTILE / 256; k++) {
        int idx = base + k * 256 + t;
        if (idx < e) {
            int r = rows[idx];
            uint_t payload = (uint_t)cols[idx] | ((uint_t)f2bf(vals[idx]) << 16);
            tmpA[idx] = ((u64_t)r << 32) | payload;
            atomicAdd(&lh[r >> 7], 1);
        }
    }
    __syncthreads();
    for (int d = t; d < NBUCK; d += 256) blockhist[d * RBLOCKS + blk] = lh[d];
}

__global__ __launch_bounds__(256) void scan_block_kernel(const int* __restrict__ cnt,
                                                         int* __restrict__ excl,
                                                         int* __restrict__ blksum, int n) {
    __shared__ int s[256];
    int tid = threadIdx.x;
    int i = blockIdx.x * 256 + tid;
    int v = (i < n) ? cnt[i] : 0;
    s[tid] = v; __syncthreads();
    for (int off = 1; off < 256; off <<= 1) {
        int t = (tid >= off) ? s[tid - off] : 0;
        __syncthreads();
        s[tid] += t;
        __syncthreads();
    }
    if (i < n) excl[i] = s[tid] - v;
    if (tid == 255) blksum[blockIdx.x] = s[255];
}

// single-block multi-chunk exclusive scan (in place)
__global__ __launch_bounds__(256) void scan_mid_kernel(int* __restrict__ data, int n) {
    __shared__ int s[256];
    __shared__ int carry;
    int t = threadIdx.x;
    if (t == 0) carry = 0;
    __syncthreads();
    for (int base = 0; base < n; base += 256) {
        int i = base + t;
        int v = (i < n) ? data[i] : 0;
        s[t] = v; __syncthreads();
        for (int off = 1; off < 256; off <<= 1) {
            int x = (t >= off) ? s[t - off] : 0;
            __syncthreads();
            s[t] += x;
            __syncthreads();
        }
        int excl = s[t] - v + carry;
        if (i < n) data[i] = excl;
        __syncthreads();
        if (t == 255) carry += s[255];
        __syncthreads();
    }
}

// gofs(i) = blockhist_excl(i) + blksum1(i>>8), computed inline by consumers.

__global__ __launch_bounds__(256) void radix_scatter_kernel(const u64_t* __restrict__ tmpA,
                                                            const int* __restrict__ blockhist,
                                                            const int* __restrict__ blksum1,
                                                            u64_t* __restrict__ tmpB, int e) {
    __shared__ u64_t stage[RTILE];          // 16 KB
    __shared__ int lh[NBUCK];
    __shared__ int lstart[NBUCK];
    __shared__ int lcur[NBUCK];
    __shared__ int gstart[NBUCK];
    int blk = blockIdx.x, t = threadIdx.x;
    for (int i = t; i < NBUCK; i += 256) lh[i] = 0;
    __syncthreads();
    int base = blk * RTILE;
    int cnt = min(RTILE, e - base);
    for (int k = t; k < cnt; k += 256) {
        int d = (int)(tmpA[base + k] >> 39);   // (row>>7)
        atomicAdd(&lh[d], 1);
    }
    __syncthreads();
    if (t == 0) {
        int s = 0;
        for (int d = 0; d < NBUCK; d++) { lstart[d] = s; s += lh[d]; }
    }
    __syncthreads();
    for (int d = t; d < NBUCK; d += 256) {
        lcur[d] = lstart[d];
        if (lh[d]) {
            int i = d * RBLOCKS + blk;
            gstart[d] = blockhist[i] + blksum1[i >> 8];
        }
    }
    __syncthreads();
    for (int k = t; k < cnt; k += 256) {
        u64_t it = tmpA[base + k];
        int d = (int)(it >> 39);
        int slot = atomicAdd(&lcur[d], 1);
        stage[slot] = it;
    }
    __syncthreads();
    for (int k = t; k < cnt; k += 256) {
        u64_t it = stage[k];
        int d = (int)(it >> 39);
        tmpB[gstart[d] + (k - lstart[d])] = it;
    }
}

__global__ __launch_bounds__(256) void bucket_sort_kernel(const u64_t* __restrict__ tmpB,
                                                          const int* __restrict__ blockhist,
                                                          const int* __restrict__ blksum1,
                                                          uint_t* __restrict__ csr_edge,
                                                          int* __restrict__ row_ptr, int e, int n) {
    __shared__ uint_t stage[4096];
    __shared__ int lh[128];
    __shared__ int lstart[128];
    __shared__ int lcur[128];
    int d = blockIdx.x, t = threadIdx.x;
    int i0 = d * RBLOCKS;
    int bstart = blockhist[i0] + blksum1[i0 >> 8];
    int bend;
    if (d == NBUCK - 1) bend = e;
    else {
        int i1 = (d + 1) * RBLOCKS;
        bend = blockhist[i1] + blksum1[i1 >> 8];
    }
    int len = bend - bstart;
    for (int i = t; i < 128; i += 256) lh[i] = 0;
    __syncthreads();
    for (int k = t; k < len; k += 256) {
        int lr = (int)((tmpB[bstart + k] >> 32) & 127);
        atomicAdd(&lh[lr], 1);
    }
    __syncthreads();
    if (t == 0) {
        int s = 0;
        for (int j = 0; j < 128; j++) { lstart[j] = s; s += lh[j]; }
    }
    __syncthreads();
    if (t < 128) {
        int grow = d * 128 + t;
        if (grow <= n) row_ptr[grow] = bstart + lstart[t];
    }
    for (int i = t; i < 128; i += 256) lcur[i] = lstart[i];
    __syncthreads();
    for (int k = t; k < len; k += 256) {
        u64_t it = tmpB[bstart + k];
        int lr = (int)((it >> 32) & 127);
        int slot = atomicAdd(&lcur[lr], 1);
        stage[slot] = (uint_t)it;
    }
    __syncthreads();
    for (int k = t; k < len; k += 256) csr_edge[bstart + k] = stage[k];
}

// ---------------- GEMM1 (MFMA): y = bf16(node_emb + type_emb[tid]) @ bf16(W1) -> bf16 [N,128] ----------------

__global__ __launch_bounds__(256) void gemm1_mfma_kernel(const float* __restrict__ node_emb,
                                                         const float* __restrict__ type_emb,
                                                         const int* __restrict__ tids,
                                                         const ushort_t* __restrict__ Wt1,
                                                         ushort_t* __restrict__ y, int n) {
    __shared__ __align__(16) ushort_t As[64 * 128];    // 16 KB
    __shared__ __align__(16) ushort_t Ws[128 * 128];   // 32 KB
    int t = threadIdx.x;

    for (int gi = t; gi < 2048; gi += 256) {
        int c = gi >> 4, kg = gi & 15;
        ushort8v v = *(const ushort8v*)&Wt1[gi * 8];
        *(ushort8v*)&Ws[c * 128 + ((kg ^ (c & 7)) << 3)] = v;
    }
    int row_l = t >> 2;
    int row_g = blockIdx.x * 64 + row_l;
    int kseg = (t & 3) * 32;
    if (row_g < n) {
        int tv = tids[row_g];
        const float4* na = (const float4*)(node_emb + (size_t)row_g * 128 + kseg);
        const float4* ta = (const float4*)(type_emb + (size_t)tv * 128 + kseg);
#pragma unroll
        for (int i2 = 0; i2 < 4; i2++) {
            float4 a = na[i2 * 2], b = ta[i2 * 2];
            float4 a2 = na[i2 * 2 + 1], b2 = ta[i2 * 2 + 1];
            ushort8v o;
            o[0] = f2bf(a.x + b.x);  o[1] = f2bf(a.y + b.y);
            o[2] = f2bf(a.z + b.z);  o[3] = f2bf(a.w + b.w);
            o[4] = f2bf(a2.x + b2.x); o[5] = f2bf(a2.y + b2.y);
            o[6] = f2bf(a2.z + b2.z); o[7] = f2bf(a2.w + b2.w);
            int kg = (t & 3) * 4 + i2;
            *(ushort8v*)&As[row_l * 128 + ((kg ^ (row_l & 7)) << 3)] = o;
        }
    } else {
        ushort8v z = (ushort8v)(ushort_t)0;
#pragma unroll
        for (int i2 = 0; i2 < 4; i2++) {
            int kg = (t & 3) * 4 + i2;
            *(ushort8v*)&As[row_l * 128 + ((kg ^ (row_l & 7)) << 3)] = z;
        }
    }
    __syncthreads();

    int lane = t & 63, wid = t >> 6;
    int m0 = (wid & 1) * 32, n0 = (wid >> 1) * 64;
    int lr = lane & 15, lk = lane >> 4;
    f32x4 acc[2][4] = {};
#pragma unroll
    for (int ks = 0; ks < 4; ks++) {
        int kg = ks * 4 + lk;
        bf16x8 afr[2];
#pragma unroll
        for (int mt = 0; mt < 2; mt++) {
            int r = m0 + mt * 16 + lr;
            afr[mt] = *(const bf16x8*)&As[r * 128 + ((kg ^ (r & 7)) << 3)];
        }
#pragma unroll
        for (int nt = 0; nt < 4; nt++) {
            int c = n0 + nt * 16 + lr;
            bf16x8 bfr = *(const bf16x8*)&Ws[c * 128 + ((kg ^ (c & 7)) << 3)];
            acc[0][nt] = __builtin_amdgcn_mfma_f32_16x16x32_bf16(afr[0], bfr, acc[0][nt], 0, 0, 0);
            acc[1][nt] = __builtin_amdgcn_mfma_f32_16x16x32_bf16(afr[1], bfr, acc[1][nt], 0, 0, 0);
        }
    }
#pragma unroll
    for (int mt = 0; mt < 2; mt++) {
#pragma unroll
        for (int j = 0; j < 4; j++) {
            int rg = blockIdx.x * 64 + m0 + mt * 16 + lk * 4 + j;
            if (rg < n) {
#pragma unroll
                for (int nt = 0; nt < 4; nt++) {
                    int c = n0 + nt * 16 + lr;
                    y[(size_t)rg * 128 + c] = f2bf(acc[mt][nt][j]);
                }
            }
        }
    }
}

// ---------------- GEMM2 (MFMA): g = h(bf16) @ bf16(W2) -> bf16 [N,64] ----------------

__global__ __launch_bounds__(256) void gemm2_mfma_kernel(const ushort_t* __restrict__ h,
                                                         const ushort_t* __restrict__ Wt2,
                                                         ushort_t* __restrict__ g, int n) {
    __shared__ __align__(16) ushort_t As[64 * 128];    // 16 KB
    __shared__ __align__(16) ushort_t Ws[64 * 128];    // 16 KB
    int t = threadIdx.x;

    for (int gi = t; gi < 1024; gi += 256) {
        int c = gi >> 4, kg = gi & 15;
        ushort8v v = *(const ushort8v*)&Wt2[gi * 8];
        *(ushort8v*)&Ws[c * 128 + ((kg ^ (c & 7)) << 3)] = v;
    }
    int row_l = t >> 2;
    int row_g = blockIdx.x * 64 + row_l;
    int kseg = (t & 3) * 32;
    if (row_g < n) {
        const ushort8v* hr = (const ushort8v*)(h + (size_t)row_g * 128 + kseg);
#pragma unroll
        for (int i2 = 0; i2 < 4; i2++) {
            ushort8v v = hr[i2];
            int kg = (t & 3) * 4 + i2;
            *(ushort8v*)&As[row_l * 128 + ((kg ^ (row_l & 7)) << 3)] = v;
        }
    } else {
        ushort8v z = (ushort8v)(ushort_t)0;
#pragma unroll
        for (int i2 = 0; i2 < 4; i2++) {
            int kg = (t & 3) * 4 + i2;
            *(ushort8v*)&As[row_l * 128 + ((kg ^ (row_l & 7)) << 3)] = z;
        }
    }
    __syncthreads();

    int lane = t & 63, wid = t >> 6;
    int m0 = (wid & 1) * 32, n0 = (wid >> 1) * 32;
    int lr = lane & 15, lk = lane >> 4;
    f32x4 acc[2][2] = {};
#pragma unroll
    for (int ks = 0; ks < 4; ks++) {
        int kg = ks * 4 + lk;
        bf16x8 afr[2];
#pragma unroll
        for (int mt = 0; mt < 2; mt++) {
            int r = m0 + mt * 16 + lr;
            afr[mt] = *(const bf16x8*)&As[r * 128 + ((kg ^ (r & 7)) << 3)];
        }
#pragma unroll
        for (int nt = 0; nt < 2; nt++) {
            int c = n0 + nt * 16 + lr;
            bf16x8 bfr = *(const bf16x8*)&Ws[c * 128 + ((kg ^ (c & 7)) << 3)];
            acc[0][nt] = __builtin_amdgcn_mfma_f32_16x16x32_bf16(afr[0], bfr, acc[0][nt], 0, 0, 0);
            acc[1][nt] = __builtin_amdgcn_mfma_f32_16x16x32_bf16(afr[1], bfr, acc[1][nt], 0, 0, 0);
        }
    }
#pragma unroll
    for (int mt = 0; mt < 2; mt++) {
#pragma unroll
        for (int j = 0; j < 4; j++) {
            int rg = blockIdx.x * 64 + m0 + mt * 16 + lk * 4 + j;
            if (rg < n) {
#pragma unroll
                for (int nt = 0; nt < 2; nt++) {
                    int c = n0 + nt * 16 + lr;
                    g[(size_t)rg * 64 + c] = f2bf(acc[mt][nt][j]);
                }
            }
        }
    }
}

// ---------------- SpMM v7: v6 with 8-wide edge unroll (8 independent gathers in flight) ----------------
// One F/8-lane group per row, 8 cols/lane, no cross-lane reduction. Per-column accumulation order
// strictly sequential in j -> bit-identical to v4/v6.

template <int F, bool RELU, bool BF16OUT>
__global__ __launch_bounds__(256) void spmm_v7_kernel(const int* __restrict__ row_ptr,
                                                      const uint_t* __restrict__ csr_edge,
                                                      const ushort_t* __restrict__ src,
                                                      const float* __restrict__ bias,
                                                      void* __restrict__ dst, int n) {
    constexpr int GL = F / 8;           // lanes per group (16 or 8)
    constexpr int RPB = (64 / GL) * 4;  // rows per block (16 or 32)
    int t = threadIdx.x;
    int lane = t & 63, wid = t >> 6;
    int gl = lane % GL;
    int gbase = lane - gl;
    int row = blockIdx.x * RPB + wid * (64 / GL) + (lane / GL);
    int c8 = gl * 8;
    if (row >= n) return;
    int start = row_ptr[row], end = row_ptr[row + 1];

    float acc[8] = {};
    for (int base = start; base < end; base += GL) {
        int idx = base + gl;
        uint_t pe = (idx < end) ? csr_edge[idx] : 0u;
        int cnt = min(GL, end - base);
        int j = 0;
        for (; j + 8 <= cnt; j += 8) {
            uint_t p[8];
#pragma unroll
            for (int u = 0; u < 8; u++) p[u] = (uint_t)__shfl((int)pe, gbase + j + u);
            ushort8v s[8];
#pragma unroll
            for (int u = 0; u < 8; u++) s[u] = *(const ushort8v*)(src + (size_t)(p[u] & 0xFFFF) * F + c8);
#pragma unroll
            for (int u = 0; u < 8; u++) {
                float vv = bf2f((ushort_t)(p[u] >> 16));
#pragma unroll
                for (int m = 0; m < 8; m++) acc[m] += vv * bf2f(s[u][m]);
            }
        }
        for (; j + 4 <= cnt; j += 4) {
            uint_t p[4];
#pragma unroll
            for (int u = 0; u < 4; u++) p[u] = (uint_t)__shfl((int)pe, gbase + j + u);
            ushort8v s[4];
#pragma unroll
            for (int u = 0; u < 4; u++) s[u] = *(const ushort8v*)(src + (size_t)(p[u] & 0xFFFF) * F + c8);
#pragma unroll
            for (int u = 0; u < 4; u++) {
                float vv = bf2f((ushort_t)(p[u] >> 16));
#pragma unroll
                for (int m = 0; m < 8; m++) acc[m] += vv * bf2f(s[u][m]);
            }
        }
        for (; j < cnt; j++) {
            uint_t p = (uint_t)__shfl((int)pe, gbase + j);
            int cc = p & 0xFFFF;
            float vv = bf2f((ushort_t)(p >> 16));
            const ushort8v s = *(const ushort8v*)(src + (size_t)cc * F + c8);
#pragma unroll
            for (int m = 0; m < 8; m++) acc[m] += vv * bf2f(s[m]);
        }
    }
#pragma unroll
    for (int m = 0; m < 8; m++) {
        acc[m] += bias[c8 + m];
        if (RELU) acc[m] = fmaxf(acc[m], 0.f);
    }
    if (BF16OUT) {
        ushort8v o;
#pragma unroll
        for (int m = 0; m < 8; m++) o[m] = f2bf(acc[m]);
        *(ushort8v*)((ushort_t*)dst + (size_t)row * F + c8) = o;
    } else {
        float4 o0 = make_float4(acc[0], acc[1], acc[2], acc[3]);
        float4 o1 = make_float4(acc[4], acc[5], acc[6], acc[7]);
        *(float4*)((float*)dst + (size_t)row * F + c8) = o0;
        *(float4*)((float*)dst + (size_t)row * F + c8 + 4) = o1;
    }
}

// ---------------- Pair scorer (MFMA): feat[64,192](bf16) @ Wp1(bf16) -> relu -> @Wp2 (f32) ----------------

__global__ __launch_bounds__(256) void pair_mfma_kernel(const int* __restrict__ pairs,
                                                        const float* __restrict__ z,
                                                        const ushort_t* __restrict__ Wtp1,
                                                        const float* __restrict__ bp1,
                                                        const float* __restrict__ Wp2,
                                                        const float* __restrict__ bp2,
                                                        float* __restrict__ out) {
    __shared__ __align__(16) ushort_t Fs[64 * 192];   // 24 KB (feat, swizzled)
    __shared__ __align__(16) ushort_t Ws[64 * 192];   // 24 KB (Wp1^T, swizzled)
    int t = threadIdx.x;

    for (int gi = t; gi < 1536; gi += 256) {
        int c = gi / 24, kg = gi % 24;
        ushort8v v = *(const ushort8v*)&Wtp1[(size_t)gi * 8];
        *(ushort8v*)&Ws[c * 192 + ((kg ^ (c & 7)) << 3)] = v;
    }
    int row_l = t >> 2;
    int rg = blockIdx.x * 64 + row_l;
    int p0 = pairs[rg], p1 = pairs[NPAIRS + rg];
    const float* z0 = z + (size_t)p0 * 64;
    const float* z1 = z + (size_t)p1 * 64;
    int q = t & 3;
#pragma unroll
    for (int i = 0; i < 6; i++) {
        int kg = q * 6 + i;          // 0..23
        int k0 = kg * 8;
        float v[8];
        if (k0 < 64) {
#pragma unroll
            for (int m = 0; m < 8; m++) v[m] = z0[k0 + m];
        } else if (k0 < 128) {
#pragma unroll
            for (int m = 0; m < 8; m++) v[m] = z1[k0 - 64 + m];
        } else {
#pragma unroll
            for (int m = 0; m < 8; m++) v[m] = z0[k0 - 128 + m] * z1[k0 - 128 + m];
        }
        ushort8v o;
#pragma unroll
        for (int m = 0; m < 8; m++) o[m] = f2bf(v[m]);
        *(ushort8v*)&Fs[row_l * 192 + ((kg ^ (row_l & 7)) << 3)] = o;
    }
    __syncthreads();

    int lane = t & 63, wid = t >> 6;
    int m0 = wid * 16;
    int lr = lane & 15, lk = lane >> 4;
    f32x4 acc[4] = {};
#pragma unroll
    for (int ks = 0; ks < 6; ks++) {
        int kg = ks * 4 + lk;
        int r = m0 + lr;
        bf16x8 afr = *(const bf16x8*)&Fs[r * 192 + ((kg ^ (r & 7)) << 3)];
#pragma unroll
        for (int nt = 0; nt < 4; nt++) {
            int c = nt * 16 + lr;
            bf16x8 bfr = *(const bf16x8*)&Ws[c * 192 + ((kg ^ (c & 7)) << 3)];
            acc[nt] = __builtin_amdgcn_mfma_f32_16x16x32_bf16(afr, bfr, acc[nt], 0, 0, 0);
        }
    }
    float s[4] = {};
#pragma unroll
    for (int nt = 0; nt < 4; nt++) {
        int c = nt * 16 + lr;
        float b = bp1[c], w = Wp2[c];
#pragma unroll
        for (int j = 0; j < 4; j++) s[j] += fmaxf(acc[nt][j] + b, 0.f) * w;
    }
#pragma unroll
    for (int j = 0; j < 4; j++) {
        s[j] += __shfl_xor(s[j], 1);
        s[j] += __shfl_xor(s[j], 2);
        s[j] += __shfl_xor(s[j], 4);
        s[j] += __shfl_xor(s[j], 8);
    }
    if (lr == 0) {
        float bb = bp2[0];
#pragma unroll
        for (int j = 0; j < 4; j++)
            out[blockIdx.x * 64 + m0 + lk * 4 + j] = s[j] + bb;
    }
}

// ---------------- launch ----------------

extern "C" void kernel_launch(void* const* d_in, const int* in_sizes, int n_in,
                              void* d_out, int out_size, void* d_ws, size_t ws_size,
                              hipStream_t stream) {
    const int*   tids     = (const int*)d_in[0];
    const int*   adj_rows = (const int*)d_in[1];
    const int*   adj_cols = (const int*)d_in[2];
    const float* adj_vals = (const float*)d_in[3];
    const int*   pairs    = (const int*)d_in[4];
    const float* node_emb = (const float*)d_in[5];
    const float* type_emb = (const float*)d_in[6];
    const float* W1  = (const float*)d_in[7];
    const float* b1  = (const float*)d_in[8];
    const float* W2  = (const float*)d_in[9];
    const float* b2  = (const float*)d_in[10];
    const float* Wp1 = (const float*)d_in[11];
    const float* bp1 = (const float*)d_in[12];
    const float* Wp2 = (const float*)d_in[13];
    const float* bp2 = (const float*)d_in[14];
    float* out = (float*)d_out;

    int n = in_sizes[0];
    int e = in_sizes[1];
    int p = in_sizes[4] / 2;

    char* ws = (char*)d_ws;
    // region A (12.8 MB): tmpA u64[e] -> y bf16 [n,128] -> g bf16 [n,64]
    ushort_t* bufY = (ushort_t*)ws;
    u64_t* tmpA = (u64_t*)ws;
    // region B (12.8 MB): tmpB u64[e] -> h bf16 [n,128] -> z f32 [n,64]
    char* wsB = ws + (size_t)n * 128 * sizeof(ushort_t);
    ushort_t* bufH = (ushort_t*)wsB;
    float* bufZ = (float*)wsB;
    u64_t* tmpB = (u64_t*)wsB;

    int* row_ptr   = (int*)(wsB + (size_t)n * 128 * sizeof(ushort_t));  // n+1
    int* blockhist = row_ptr + (n + 1);                   // NBUCK*RBLOCKS
    int L  = NBUCK * RBLOCKS;                             // 152881
    int* blksum1   = blockhist + L;                       // <=1024
    uint_t* csr_edge = (uint_t*)(blksum1 + 1024);         // e (packed u32)
    ushort_t* Wt1 = (ushort_t*)(csr_edge + e);            // 128*128 bf16
    ushort_t* Wt2 = Wt1 + 128 * 128;                      // 64*128 bf16
    ushort_t* Wtp1 = Wt2 + 64 * 128;                      // 64*192 bf16

    int SG = (L + 255) / 256;                             // 598

    pack_hist_prep_kernel<<<RBLOCKS + 18, 256, 0, stream>>>(adj_rows, adj_cols, adj_vals, tmpA, blockhist, e,
                                                            W1, W2, Wp1, Wt1, Wt2, Wtp1);
    scan_block_kernel<<<SG, 256, 0, stream>>>(blockhist, blockhist, blksum1, L);
    scan_mid_kernel<<<1, 256, 0, stream>>>(blksum1, SG);
    radix_scatter_kernel<<<RBLOCKS, 256, 0, stream>>>(tmpA, blockhist, blksum1, tmpB, e);
    bucket_sort_kernel<<<NBUCK, 256, 0, stream>>>(tmpB, blockhist, blksum1, csr_edge, row_ptr, e, n);

    gemm1_mfma_kernel<<<(n + 63) / 64, 256, 0, stream>>>(node_emb, type_emb, tids, Wt1, bufY, n);
    spmm_v7_kernel<128, true, true><<<(n + 15) / 16, 256, 0, stream>>>(row_ptr, csr_edge, bufY, b1, bufH, n);
    gemm2_mfma_kernel<<<(n + 63) / 64, 256, 0, stream>>>(bufH, Wt2, bufY, n);   // g -> region A
    spmm_v7_kernel<64, false, false><<<(n + 31) / 32, 256, 0, stream>>>(row_ptr, csr_edge, bufY, b2, bufZ, n);
    pair_mfma_kernel<<<p / 64, 256, 0, stream>>>(pairs, bufZ, Wtp1, bp1, Wp2, bp2, out);
}

// Round 24
// 133.740 us; speedup vs baseline: 1.0837x; 1.0062x over previous
//
#include <hip/hip_runtime.h>

#define N_NODES 50000
#define N_EDGES 800000
#define NPAIRS  65536

#define NBUCK 391          // ceil(N_NODES/128): coarse bucket = row>>7
#define RTILE 4096
#define RBLOCKS 196        // ceil(N_EDGES/RTILE)

typedef unsigned short ushort_t;
typedef unsigned int uint_t;
typedef unsigned long long u64_t;
typedef ushort_t ushort8v __attribute__((ext_vector_type(8)));
typedef short bf16x8 __attribute__((ext_vector_type(8)));
typedef float f32x4 __attribute__((ext_vector_type(4)));

__device__ inline ushort_t f2bf(float f) {
    uint_t u = __float_as_uint(f);
    u = (u + 0x7FFF + ((u >> 16) & 1)) >> 16;   // RTN-even
    return (ushort_t)u;
}
__device__ inline float bf2f(ushort_t b) {
    return __uint_as_float(((uint_t)b) << 16);
}

// ---------------- W prep (first launch; Wt1 must exist before fused pack+gemm1) ----------------

__global__ __launch_bounds__(256) void prep_w_kernel(const float* __restrict__ W1,
                                                     const float* __restrict__ W2,
                                                     const float* __restrict__ Wp1,
                                                     ushort_t* __restrict__ Wt1,
                                                     ushort_t* __restrict__ Wt2,
                                                     ushort_t* __restrict__ Wtp1) {
    int g = blockIdx.x * 256 + threadIdx.x;   // granule id
    if (g < 2048) {           // W1: g = k8*128 + c
        int c = g & 127, k8 = g >> 7;
        ushort8v o;
#pragma unroll
        for (int j = 0; j < 8; j++) o[j] = f2bf(W1[(size_t)(k8 * 8 + j) * 128 + c]);
        *(ushort8v*)&Wt1[(size_t)c * 128 + k8 * 8] = o;
    } else if (g < 3072) {    // W2: g2 = k8*64 + c
        int g2 = g - 2048;
        int c = g2 & 63, k8 = g2 >> 6;
        ushort8v o;
#pragma unroll
        for (int j = 0; j < 8; j++) o[j] = f2bf(W2[(size_t)(k8 * 8 + j) * 64 + c]);
        *(ushort8v*)&Wt2[(size_t)c * 128 + k8 * 8] = o;
    } else if (g < 4608) {    // Wp1: g2 = c*24 + k8
        int g2 = g - 3072;
        int c = g2 / 24, k8 = g2 % 24;
        ushort8v o;
#pragma unroll
        for (int j = 0; j < 8; j++) o[j] = f2bf(Wp1[(size_t)(k8 * 8 + j) * 64 + c]);
        *(ushort8v*)&Wtp1[(size_t)g2 * 8] = o;
    }
}

// ---------------- Fused: pack edges + per-block hist  ||  GEMM1 (independent work, one launch) ----------------
// blocks [0, RBLOCKS): pack+hist. blocks [RBLOCKS, RBLOCKS + (n+63)/64): gemm1 (reads Wt1 from prep launch).
// y has its OWN region (no aliasing with tmpA) so both halves can run concurrently.

__global__ __launch_bounds__(256) void pack_gemm1_kernel(const int* __restrict__ rows,
                                                         const int* __restrict__ cols,
                                                         const float* __restrict__ vals,
                                                         u64_t* __restrict__ tmpA,
                                                         int* __restrict__ blockhist, int e,
                                                         const float* __restrict__ node_emb,
                                                         const float* __restrict__ type_emb,
                                                         const int* __restrict__ tids,
                                                         const ushort_t* __restrict__ Wt1,
                                                         ushort_t* __restrict__ y, int n) {
    __shared__ __align__(16) char smem[49152];   // union: gemm1 As(16K)+Ws(32K) | pack lh(1.6K)
    int t = threadIdx.x;

    if (blockIdx.x < RBLOCKS) {
        int* lh = (int*)smem;
        int blk = blockIdx.x;
        for (int i = t; i < NBUCK; i += 256) lh[i] = 0;
        __syncthreads();
        int base = blk * RTILE;
#pragma unroll
        for (int k = 0; k < RTILE / 256; k++) {
            int idx = base + k * 256 + t;
            if (idx < e) {
                int r = rows[idx];
                uint_t payload = (uint_t)cols[idx] | ((uint_t)f2bf(vals[idx]) << 16);
                tmpA[idx] = ((u64_t)r << 32) | payload;
                atomicAdd(&lh[r >> 7], 1);
            }
        }
        __syncthreads();
        for (int d = t; d < NBUCK; d += 256) blockhist[d * RBLOCKS + blk] = lh[d];
        return;
    }

    // ---- gemm1 path ----
    ushort_t* As = (ushort_t*)smem;              // 64*128
    ushort_t* Ws = (ushort_t*)(smem + 16384);    // 128*128
    int bid = blockIdx.x - RBLOCKS;

    for (int gi = t; gi < 2048; gi += 256) {
        int c = gi >> 4, kg = gi & 15;
        ushort8v v = *(const ushort8v*)&Wt1[gi * 8];
        *(ushort8v*)&Ws[c * 128 + ((kg ^ (c & 7)) << 3)] = v;
    }
    int row_l = t >> 2;
    int row_g = bid * 64 + row_l;
    int kseg = (t & 3) * 32;
    if (row_g < n) {
        int tv = tids[row_g];
        const float4* na = (const float4*)(node_emb + (size_t)row_g * 128 + kseg);
        const float4* ta = (const float4*)(type_emb + (size_t)tv * 128 + kseg);
#pragma unroll
        for (int i2 = 0; i2 < 4; i2++) {
            float4 a = na[i2 * 2], b = ta[i2 * 2];
            float4 a2 = na[i2 * 2 + 1], b2 = ta[i2 * 2 + 1];
            ushort8v o;
            o[0] = f2bf(a.x + b.x);  o[1] = f2bf(a.y + b.y);
            o[2] = f2bf(a.z + b.z);  o[3] = f2bf(a.w + b.w);
            o[4] = f2bf(a2.x + b2.x); o[5] = f2bf(a2.y + b2.y);
            o[6] = f2bf(a2.z + b2.z); o[7] = f2bf(a2.w + b2.w);
            int kg = (t & 3) * 4 + i2;
            *(ushort8v*)&As[row_l * 128 + ((kg ^ (row_l & 7)) << 3)] = o;
        }
    } else {
        ushort8v z = (ushort8v)(ushort_t)0;
#pragma unroll
        for (int i2 = 0; i2 < 4; i2++) {
            int kg = (t & 3) * 4 + i2;
            *(ushort8v*)&As[row_l * 128 + ((kg ^ (row_l & 7)) << 3)] = z;
        }
    }
    __syncthreads();

    int lane = t & 63, wid = t >> 6;
    int m0 = (wid & 1) * 32, n0 = (wid >> 1) * 64;
    int lr = lane & 15, lk = lane >> 4;
    f32x4 acc[2][4] = {};
#pragma unroll
    for (int ks = 0; ks < 4; ks++) {
        int kg = ks * 4 + lk;
        bf16x8 afr[2];
#pragma unroll
        for (int mt = 0; mt < 2; mt++) {
            int r = m0 + mt * 16 + lr;
            afr[mt] = *(const bf16x8*)&As[r * 128 + ((kg ^ (r & 7)) << 3)];
        }
#pragma unroll
        for (int nt = 0; nt < 4; nt++) {
            int c = n0 + nt * 16 + lr;
            bf16x8 bfr = *(const bf16x8*)&Ws[c * 128 + ((kg ^ (c & 7)) << 3)];
            acc[0][nt] = __builtin_amdgcn_mfma_f32_16x16x32_bf16(afr[0], bfr, acc[0][nt], 0, 0, 0);
            acc[1][nt] = __builtin_amdgcn_mfma_f32_16x16x32_bf16(afr[1], bfr, acc[1][nt], 0, 0, 0);
        }
    }
#pragma unroll
    for (int mt = 0; mt < 2; mt++) {
#pragma unroll
        for (int j = 0; j < 4; j++) {
            int rg = bid * 64 + m0 + mt * 16 + lk * 4 + j;
            if (rg < n) {
#pragma unroll
                for (int nt = 0; nt < 4; nt++) {
                    int c = n0 + nt * 16 + lr;
                    y[(size_t)rg * 128 + c] = f2bf(acc[mt][nt][j]);
                }
            }
        }
    }
}

__global__ __launch_bounds__(256) void scan_block_kernel(const int* __restrict__ cnt,
                                                         int* __restrict__ excl,
                                                         int* __restrict__ blksum, int n) {
    __shared__ int s[256];
    int tid = threadIdx.x;
    int i = blockIdx.x * 256 + tid;
    int v = (i < n) ? cnt[i] : 0;
    s[tid] = v; __syncthreads();
    for (int off = 1; off < 256; off <<= 1) {
        int t = (tid >= off) ? s[tid - off] : 0;
        __syncthreads();
        s[tid] += t;
        __syncthreads();
    }
    if (i < n) excl[i] = s[tid] - v;
    if (tid == 255) blksum[blockIdx.x] = s[255];
}

// single-block multi-chunk exclusive scan (in place)
__global__ __launch_bounds__(256) void scan_mid_kernel(int* __restrict__ data, int n) {
    __shared__ int s[256];
    __shared__ int carry;
    int t = threadIdx.x;
    if (t == 0) carry = 0;
    __syncthreads();
    for (int base = 0; base < n; base += 256) {
        int i = base + t;
        int v = (i < n) ? data[i] : 0;
        s[t] = v; __syncthreads();
        for (int off = 1; off < 256; off <<= 1) {
            int x = (t >= off) ? s[t - off] : 0;
            __syncthreads();
            s[t] += x;
            __syncthreads();
        }
        int excl = s[t] - v + carry;
        if (i < n) data[i] = excl;
        __syncthreads();
        if (t == 255) carry += s[255];
        __syncthreads();
    }
}

// gofs(i) = blockhist_excl(i) + blksum1(i>>8), computed inline by consumers.

__global__ __launch_bounds__(256) void radix_scatter_kernel(const u64_t* __restrict__ tmpA,
                                                            const int* __restrict__ blockhist,
                                                            const int* __restrict__ blksum1,
                                                            u64_t* __restrict__ tmpB, int e) {
    __shared__ u64_t stage[RTILE];          // 32 KB
    __shared__ int lh[NBUCK];
    __shared__ int lstart[NBUCK];
    __shared__ int lcur[NBUCK];
    __shared__ int gstart[NBUCK];
    int blk = blockIdx.x, t = threadIdx.x;
    for (int i = t; i < NBUCK; i += 256) lh[i] = 0;
    __syncthreads();
    int base = blk * RTILE;
    int cnt = min(RTILE, e - base);
    for (int k = t; k < cnt; k += 256) {
        int d = (int)(tmpA[base + k] >> 39);   // (row>>7)
        atomicAdd(&lh[d], 1);
    }
    __syncthreads();
    if (t == 0) {
        int s = 0;
        for (int d = 0; d < NBUCK; d++) { lstart[d] = s; s += lh[d]; }
    }
    __syncthreads();
    for (int d = t; d < NBUCK; d += 256) {
        lcur[d] = lstart[d];
        if (lh[d]) {
            int i = d * RBLOCKS + blk;
            gstart[d] = blockhist[i] + blksum1[i >> 8];
        }
    }
    __syncthreads();
    for (int k = t; k < cnt; k += 256) {
        u64_t it = tmpA[base + k];
        int d = (int)(it >> 39);
        int slot = atomicAdd(&lcur[d], 1);
        stage[slot] = it;
    }
    __syncthreads();
    for (int k = t; k < cnt; k += 256) {
        u64_t it = stage[k];
        int d = (int)(it >> 39);
        tmpB[gstart[d] + (k - lstart[d])] = it;
    }
}

__global__ __launch_bounds__(256) void bucket_sort_kernel(const u64_t* __restrict__ tmpB,
                                                          const int* __restrict__ blockhist,
                                                          const int* __restrict__ blksum1,
                                                          uint_t* __restrict__ csr_edge,
                                                          int* __restrict__ row_ptr, int e, int n) {
    __shared__ uint_t stage[4096];
    __shared__ int lh[128];
    __shared__ int lstart[128];
    __shared__ int lcur[128];
    int d = blockIdx.x, t = threadIdx.x;
    int i0 = d * RBLOCKS;
    int bstart = blockhist[i0] + blksum1[i0 >> 8];
    int bend;
    if (d == NBUCK - 1) bend = e;
    else {
        int i1 = (d + 1) * RBLOCKS;
        bend = blockhist[i1] + blksum1[i1 >> 8];
    }
    int len = bend - bstart;
    for (int i = t; i < 128; i += 256) lh[i] = 0;
    __syncthreads();
    for (int k = t; k < len; k += 256) {
        int lr = (int)((tmpB[bstart + k] >> 32) & 127);
        atomicAdd(&lh[lr], 1);
    }
    __syncthreads();
    if (t == 0) {
        int s = 0;
        for (int j = 0; j < 128; j++) { lstart[j] = s; s += lh[j]; }
    }
    __syncthreads();
    if (t < 128) {
        int grow = d * 128 + t;
        if (grow <= n) row_ptr[grow] = bstart + lstart[t];
    }
    for (int i = t; i < 128; i += 256) lcur[i] = lstart[i];
    __syncthreads();
    for (int k = t; k < len; k += 256) {
        u64_t it = tmpB[bstart + k];
        int lr = (int)((it >> 32) & 127);
        int slot = atomicAdd(&lcur[lr], 1);
        stage[slot] = (uint_t)it;
    }
    __syncthreads();
    for (int k = t; k < len; k += 256) csr_edge[bstart + k] = stage[k];
}

// ---------------- GEMM2 (MFMA): g = h(bf16) @ bf16(W2) -> bf16 [N,64] ----------------

__global__ __launch_bounds__(256) void gemm2_mfma_kernel(const ushort_t* __restrict__ h,
                                                         const ushort_t* __restrict__ Wt2,
                                                         ushort_t* __restrict__ g, int n) {
    __shared__ __align__(16) ushort_t As[64 * 128];    // 16 KB
    __shared__ __align__(16) ushort_t Ws[64 * 128];    // 16 KB
    int t = threadIdx.x;

    for (int gi = t; gi < 1024; gi += 256) {
        int c = gi >> 4, kg = gi & 15;
        ushort8v v = *(const ushort8v*)&Wt2[gi * 8];
        *(ushort8v*)&Ws[c * 128 + ((kg ^ (c & 7)) << 3)] = v;
    }
    int row_l = t >> 2;
    int row_g = blockIdx.x * 64 + row_l;
    int kseg = (t & 3) * 32;
    if (row_g < n) {
        const ushort8v* hr = (const ushort8v*)(h + (size_t)row_g * 128 + kseg);
#pragma unroll
        for (int i2 = 0; i2 < 4; i2++) {
            ushort8v v = hr[i2];
            int kg = (t & 3) * 4 + i2;
            *(ushort8v*)&As[row_l * 128 + ((kg ^ (row_l & 7)) << 3)] = v;
        }
    } else {
        ushort8v z = (ushort8v)(ushort_t)0;
#pragma unroll
        for (int i2 = 0; i2 < 4; i2++) {
            int kg = (t & 3) * 4 + i2;
            *(ushort8v*)&As[row_l * 128 + ((kg ^ (row_l & 7)) << 3)] = z;
        }
    }
    __syncthreads();

    int lane = t & 63, wid = t >> 6;
    int m0 = (wid & 1) * 32, n0 = (wid >> 1) * 32;
    int lr = lane & 15, lk = lane >> 4;
    f32x4 acc[2][2] = {};
#pragma unroll
    for (int ks = 0; ks < 4; ks++) {
        int kg = ks * 4 + lk;
        bf16x8 afr[2];
#pragma unroll
        for (int mt = 0; mt < 2; mt++) {
            int r = m0 + mt * 16 + lr;
            afr[mt] = *(const bf16x8*)&As[r * 128 + ((kg ^ (r & 7)) << 3)];
        }
#pragma unroll
        for (int nt = 0; nt < 2; nt++) {
            int c = n0 + nt * 16 + lr;
            bf16x8 bfr = *(const bf16x8*)&Ws[c * 128 + ((kg ^ (c & 7)) << 3)];
            acc[0][nt] = __builtin_amdgcn_mfma_f32_16x16x32_bf16(afr[0], bfr, acc[0][nt], 0, 0, 0);
            acc[1][nt] = __builtin_amdgcn_mfma_f32_16x16x32_bf16(afr[1], bfr, acc[1][nt], 0, 0, 0);
        }
    }
#pragma unroll
    for (int mt = 0; mt < 2; mt++) {
#pragma unroll
        for (int j = 0; j < 4; j++) {
            int rg = blockIdx.x * 64 + m0 + mt * 16 + lk * 4 + j;
            if (rg < n) {
#pragma unroll
                for (int nt = 0; nt < 2; nt++) {
                    int c = n0 + nt * 16 + lr;
                    g[(size_t)rg * 64 + c] = f2bf(acc[mt][nt][j]);
                }
            }
        }
    }
}

// ---------------- SpMM v7: 8-wide edge unroll (8 independent gathers in flight) ----------------
// One F/8-lane group per row, 8 cols/lane, no cross-lane reduction. Per-column accumulation order
// strictly sequential in j -> bit-identical to v4/v6.

template <int F, bool RELU, bool BF16OUT>
__global__ __launch_bounds__(256) void spmm_v7_kernel(const int* __restrict__ row_ptr,
                                                      const uint_t* __restrict__ csr_edge,
                                                      const ushort_t* __restrict__ src,
                                                      const float* __restrict__ bias,
                                                      void* __restrict__ dst, int n) {
    constexpr int GL = F / 8;           // lanes per group (16 or 8)
    constexpr int RPB = (64 / GL) * 4;  // rows per block (16 or 32)
    int t = threadIdx.x;
    int lane = t & 63, wid = t >> 6;
    int gl = lane % GL;
    int gbase = lane - gl;
    int row = blockIdx.x * RPB + wid * (64 / GL) + (lane / GL);
    int c8 = gl * 8;
    if (row >= n) return;
    int start = row_ptr[row], end = row_ptr[row + 1];

    float acc[8] = {};
    for (int base = start; base < end; base += GL) {
        int idx = base + gl;
        uint_t pe = (idx < end) ? csr_edge[idx] : 0u;
        int cnt = min(GL, end - base);
        int j = 0;
        for (; j + 8 <= cnt; j += 8) {
            uint_t p[8];
#pragma unroll
            for (int u = 0; u < 8; u++) p[u] = (uint_t)__shfl((int)pe, gbase + j + u);
            ushort8v s[8];
#pragma unroll
            for (int u = 0; u < 8; u++) s[u] = *(const ushort8v*)(src + (size_t)(p[u] & 0xFFFF) * F + c8);
#pragma unroll
            for (int u = 0; u < 8; u++) {
                float vv = bf2f((ushort_t)(p[u] >> 16));
#pragma unroll
                for (int m = 0; m < 8; m++) acc[m] += vv * bf2f(s[u][m]);
            }
        }
        for (; j + 4 <= cnt; j += 4) {
            uint_t p[4];
#pragma unroll
            for (int u = 0; u < 4; u++) p[u] = (uint_t)__shfl((int)pe, gbase + j + u);
            ushort8v s[4];
#pragma unroll
            for (int u = 0; u < 4; u++) s[u] = *(const ushort8v*)(src + (size_t)(p[u] & 0xFFFF) * F + c8);
#pragma unroll
            for (int u = 0; u < 4; u++) {
                float vv = bf2f((ushort_t)(p[u] >> 16));
#pragma unroll
                for (int m = 0; m < 8; m++) acc[m] += vv * bf2f(s[u][m]);
            }
        }
        for (; j < cnt; j++) {
            uint_t p = (uint_t)__shfl((int)pe, gbase + j);
            int cc = p & 0xFFFF;
            float vv = bf2f((ushort_t)(p >> 16));
            const ushort8v s = *(const ushort8v*)(src + (size_t)cc * F + c8);
#pragma unroll
            for (int m = 0; m < 8; m++) acc[m] += vv * bf2f(s[m]);
        }
    }
#pragma unroll
    for (int m = 0; m < 8; m++) {
        acc[m] += bias[c8 + m];
        if (RELU) acc[m] = fmaxf(acc[m], 0.f);
    }
    if (BF16OUT) {
        ushort8v o;
#pragma unroll
        for (int m = 0; m < 8; m++) o[m] = f2bf(acc[m]);
        *(ushort8v*)((ushort_t*)dst + (size_t)row * F + c8) = o;
    } else {
        float4 o0 = make_float4(acc[0], acc[1], acc[2], acc[3]);
        float4 o1 = make_float4(acc[4], acc[5], acc[6], acc[7]);
        *(float4*)((float*)dst + (size_t)row * F + c8) = o0;
        *(float4*)((float*)dst + (size_t)row * F + c8 + 4) = o1;
    }
}

// ---------------- Pair scorer (MFMA): feat[64,192](bf16) @ Wp1(bf16) -> relu -> @Wp2 (f32) ----------------

__global__ __launch_bounds__(256) void pair_mfma_kernel(const int* __restrict__ pairs,
                                                        const float* __restrict__ z,
                                                        const ushort_t* __restrict__ Wtp1,
                                                        const float* __restrict__ bp1,
                                                        const float* __restrict__ Wp2,
                                                        const float* __restrict__ bp2,
                                                        float* __restrict__ out) {
    __shared__ __align__(16) ushort_t Fs[64 * 192];   // 24 KB (feat, swizzled)
    __shared__ __align__(16) ushort_t Ws[64 * 192];   // 24 KB (Wp1^T, swizzled)
    int t = threadIdx.x;

    for (int gi = t; gi < 1536; gi += 256) {
        int c = gi / 24, kg = gi % 24;
        ushort8v v = *(const ushort8v*)&Wtp1[(size_t)gi * 8];
        *(ushort8v*)&Ws[c * 192 + ((kg ^ (c & 7)) << 3)] = v;
    }
    int row_l = t >> 2;
    int rg = blockIdx.x * 64 + row_l;
    int p0 = pairs[rg], p1 = pairs[NPAIRS + rg];
    const float* z0 = z + (size_t)p0 * 64;
    const float* z1 = z + (size_t)p1 * 64;
    int q = t & 3;
#pragma unroll
    for (int i = 0; i < 6; i++) {
        int kg = q * 6 + i;          // 0..23
        int k0 = kg * 8;
        float v[8];
        if (k0 < 64) {
#pragma unroll
            for (int m = 0; m < 8; m++) v[m] = z0[k0 + m];
        } else if (k0 < 128) {
#pragma unroll
            for (int m = 0; m < 8; m++) v[m] = z1[k0 - 64 + m];
        } else {
#pragma unroll
            for (int m = 0; m < 8; m++) v[m] = z0[k0 - 128 + m] * z1[k0 - 128 + m];
        }
        ushort8v o;
#pragma unroll
        for (int m = 0; m < 8; m++) o[m] = f2bf(v[m]);
        *(ushort8v*)&Fs[row_l * 192 + ((kg ^ (row_l & 7)) << 3)] = o;
    }
    __syncthreads();

    int lane = t & 63, wid = t >> 6;
    int m0 = wid * 16;
    int lr = lane & 15, lk = lane >> 4;
    f32x4 acc[4] = {};
#pragma unroll
    for (int ks = 0; ks < 6; ks++) {
        int kg = ks * 4 + lk;
        int r = m0 + lr;
        bf16x8 afr = *(const bf16x8*)&Fs[r * 192 + ((kg ^ (r & 7)) << 3)];
#pragma unroll
        for (int nt = 0; nt < 4; nt++) {
            int c = nt * 16 + lr;
            bf16x8 bfr = *(const bf16x8*)&Ws[c * 192 + ((kg ^ (c & 7)) << 3)];
            acc[nt] = __builtin_amdgcn_mfma_f32_16x16x32_bf16(afr, bfr, acc[nt], 0, 0, 0);
        }
    }
    float s[4] = {};
#pragma unroll
    for (int nt = 0; nt < 4; nt++) {
        int c = nt * 16 + lr;
        float b = bp1[c], w = Wp2[c];
#pragma unroll
        for (int j = 0; j < 4; j++) s[j] += fmaxf(acc[nt][j] + b, 0.f) * w;
    }
#pragma unroll
    for (int j = 0; j < 4; j++) {
        s[j] += __shfl_xor(s[j], 1);
        s[j] += __shfl_xor(s[j], 2);
        s[j] += __shfl_xor(s[j], 4);
        s[j] += __shfl_xor(s[j], 8);
    }
    if (lr == 0) {
        float bb = bp2[0];
#pragma unroll
        for (int j = 0; j < 4; j++)
            out[blockIdx.x * 64 + m0 + lk * 4 + j] = s[j] + bb;
    }
}

// ---------------- launch ----------------

extern "C" void kernel_launch(void* const* d_in, const int* in_sizes, int n_in,
                              void* d_out, int out_size, void* d_ws, size_t ws_size,
                              hipStream_t stream) {
    const int*   tids     = (const int*)d_in[0];
    const int*   adj_rows = (const int*)d_in[1];
    const int*   adj_cols = (const int*)d_in[2];
    const float* adj_vals = (const float*)d_in[3];
    const int*   pairs    = (const int*)d_in[4];
    const float* node_emb = (const float*)d_in[5];
    const float* type_emb = (const float*)d_in[6];
    const float* W1  = (const float*)d_in[7];
    const float* b1  = (const float*)d_in[8];
    const float* W2  = (const float*)d_in[9];
    const float* b2  = (const float*)d_in[10];
    const float* Wp1 = (const float*)d_in[11];
    const float* bp1 = (const float*)d_in[12];
    const float* Wp2 = (const float*)d_in[13];
    const float* bp2 = (const float*)d_in[14];
    float* out = (float*)d_out;

    int n = in_sizes[0];
    int e = in_sizes[1];
    int p = in_sizes[4] / 2;

    char* ws = (char*)d_ws;
    // region Y (12.8 MB): y bf16 [n,128] (dedicated; enables pack || gemm1 overlap)
    ushort_t* bufY = (ushort_t*)ws;
    // region A (6.4 MB): tmpA u64[e] -> g bf16 [n,64]
    char* wsA = ws + (size_t)n * 128 * sizeof(ushort_t);
    u64_t* tmpA = (u64_t*)wsA;
    ushort_t* bufG = (ushort_t*)wsA;
    // region B (12.8 MB): tmpB u64[e] -> h bf16 [n,128] -> z f32 [n,64]
    char* wsB = wsA + (size_t)e * sizeof(u64_t);
    u64_t* tmpB = (u64_t*)wsB;
    ushort_t* bufH = (ushort_t*)wsB;
    float* bufZ = (float*)wsB;

    int* row_ptr   = (int*)(wsB + (size_t)n * 128 * sizeof(ushort_t));  // n+1
    int* blockhist = row_ptr + (n + 1);                   // NBUCK*RBLOCKS
    int L  = NBUCK * RBLOCKS;                             // 76636
    int* blksum1   = blockhist + L;                       // <=1024
    uint_t* csr_edge = (uint_t*)(blksum1 + 1024);         // e (packed u32)
    ushort_t* Wt1 = (ushort_t*)(csr_edge + e);            // 128*128 bf16
    ushort_t* Wt2 = Wt1 + 128 * 128;                      // 64*128 bf16
    ushort_t* Wtp1 = Wt2 + 64 * 128;                      // 64*192 bf16

    int SG = (L + 255) / 256;                             // 300
    int g1b = (n + 63) / 64;                              // 782

    prep_w_kernel<<<18, 256, 0, stream>>>(W1, W2, Wp1, Wt1, Wt2, Wtp1);
    pack_gemm1_kernel<<<RBLOCKS + g1b, 256, 0, stream>>>(adj_rows, adj_cols, adj_vals, tmpA, blockhist, e,
                                                         node_emb, type_emb, tids, Wt1, bufY, n);
    scan_block_kernel<<<SG, 256, 0, stream>>>(blockhist, blockhist, blksum1, L);
    scan_mid_kernel<<<1, 256, 0, stream>>>(blksum1, SG);
    radix_scatter_kernel<<<RBLOCKS, 256, 0, stream>>>(tmpA, blockhist, blksum1, tmpB, e);
    bucket_sort_kernel<<<NBUCK, 256, 0, stream>>>(tmpB, blockhist, blksum1, csr_edge, row_ptr, e, n);

    spmm_v7_kernel<128, true, true><<<(n + 15) / 16, 256, 0, stream>>>(row_ptr, csr_edge, bufY, b1, bufH, n);
    gemm2_mfma_kernel<<<(n + 63) / 64, 256, 0, stream>>>(bufH, Wt2, bufG, n);
    spmm_v7_kernel<64, false, false><<<(n + 31) / 32, 256, 0, stream>>>(row_ptr, csr_edge, bufG, b2, bufZ, n);
    pair_mfma_kernel<<<p / 64, 256, 0, stream>>>(pairs, bufZ, Wtp1, bp1, Wp2, bp2, out);
}